// Round 13
// baseline (106.862 us; speedup 1.0000x reference)
//
#include <hip/hip_runtime.h>

typedef unsigned int uint32;
typedef __attribute__((ext_vector_type(8))) _Float16 f16x8;
typedef __attribute__((ext_vector_type(8))) short bf16x8;
typedef __attribute__((ext_vector_type(4))) float f32x4;

#define NN 2048
#define FF 128
#define KEEPK 1258291u      // int(0.3 * 2048 * 2048)
#define NB 2048             // histogram bins per level
#define NCOPY1 16           // hist1 shards
#define CSHARDS 4           // colsum shards
#define LO1 (-4.0f)
#define BINW1 0.0625f       // 2^-4, exact
#define INV1 16.0f
#define INV2 32768.0f       // 2048 / BINW1 = 2^15, exact
#define CAND_CAP 131072u    // B1-bin population ~37k expected; 3.6x margin
#define LBUF 2048u          // per-block LDS candidate staging (k_h2c)
#define C2_CAP 4096u        // B2-filtered candidate capacity
#define NPART 8             // i-chunks for atomic-free aggregation
#define LO_SCALE 2048.0f    // 2^11: keep fp16 lo-part in normal range
#define LO_UNSCALE 4.8828125e-4f  // 2^-11
#define NTRI 528            // 32*33/2 upper-triangular 64x64 tiles

// workspace layout (bytes)  [ws_size = 256 MiB]
#define OFF_DEG    (0u)                 // float[2048]
#define OFF_DEGC   (8u*1024u)           // float[2048]
#define OFF_SCAL   (16u*1024u)          // uint[64]
#define OFF_HIST1  (17u*1024u)          // uint[16][2048] = 128K
#define OFF_HIST2  (145u*1024u)         // uint[2048] = 8K
#define OFF_CSUM   (153u*1024u)         // float[4][2048] = 32K
#define ZERO_BYTES (185u*1024u)
#define ZERO_F4    (11840u)             // ZERO_BYTES / 16
#define OFF_CANDV  (185u*1024u)         // float[131072] = 512K
#define OFF_CANDF  (697u*1024u)         // uint[131072]  = 512K
#define OFF_C2V    (1209u*1024u)        // float[4096] = 16K
#define OFF_C2F    (1225u*1024u)        // uint[4096]  = 16K
#define OFF_XHI    (1241u*1024u)        // fp16 hi(x) = 512K
#define OFF_XLO    (1753u*1024u)        // fp16 lo(x)*2048 = 512K
#define OFF_H      (2265u*1024u)        // float h = 1 MB
#define OFF_S      (3289u*1024u)        // float[2048*2048] = 16 MB
#define OFF_PART   (OFF_S + (uint32)NN*NN*4u)   // 8 MB
#define WS_NEEDED  ((size_t)OFF_PART + (size_t)NPART*NN*FF*4u)

// dynamic LDS carve for k_main (72 KB; transpose buffer aliases A-frags)
#define SM_AHI 0
#define SM_ALO 16384
#define SM_BHI 32768
#define SM_BLO 49152
#define SM_HS  65536
#define SM_TOTAL 73728

__device__ __forceinline__ int bin_of(float v, float lo, float inv) {
    int b = (int)floorf((v - lo) * inv);
    return b < 0 ? 0 : (b > NB - 1 ? NB - 1 : b);
}

__device__ __forceinline__ unsigned short f2bf(float f) {   // round-to-nearest-even
    uint32 u = __float_as_uint(f);
    u += 0x7fffu + ((u >> 16) & 1u);
    return (unsigned short)(u >> 16);
}

__device__ __forceinline__ void split16(float v, unsigned short& hi, unsigned short& lo) {
    union { _Float16 f; unsigned short u; } a, b;
    a.f = (_Float16)v;
    float back = (float)a.f;
    b.f = (_Float16)((v - back) * LO_SCALE);
    hi = a.u; lo = b.u;
}

__device__ __forceinline__ uint4 pack8(const unsigned short* w) {  // 8 u16 -> uint4
    uint4 p;
    p.x = (uint32)w[0] | ((uint32)w[1] << 16);
    p.y = (uint32)w[2] | ((uint32)w[3] << 16);
    p.z = (uint32)w[4] | ((uint32)w[5] << 16);
    p.w = (uint32)w[6] | ((uint32)w[7] << 16);
    return p;
}

// one-shot split of x into fp16 hi/lo + fused zeroing of the accumulator region
__global__ __launch_bounds__(256) void k_prep(const float* __restrict__ x,
                                              unsigned short* __restrict__ xhi,
                                              unsigned short* __restrict__ xlo,
                                              float4* __restrict__ zbase) {
    int id = blockIdx.x * 256 + threadIdx.x;   // 32768 threads x 8 elems
    if ((uint32)id < ZERO_F4) zbase[id] = (float4){0.f, 0.f, 0.f, 0.f};
    float4 a0 = *(const float4*)&x[(size_t)id * 8];
    float4 a1 = *(const float4*)&x[(size_t)id * 8 + 4];
    unsigned short h8[8], l8[8];
    #pragma unroll
    for (int e = 0; e < 4; ++e) {
        split16((&a0.x)[e], h8[e], l8[e]);
        split16((&a1.x)[e], h8[4 + e], l8[4 + e]);
    }
    *(uint4*)&xhi[(size_t)id * 8] = pack8(h8);
    *(uint4*)&xlo[(size_t)id * 8] = pack8(l8);
}

// blocks [0,528): upper-triangular 64x64 tile (ti<=tj) of S = X*X^T - I via
// split-fp16 MFMA; off-diag tiles mirror-written via in-LDS transpose (LDS
// buffer aliases dead A-frags); hist1 counts off-diag elements with weight 2.
// blocks [528,656): h = X*W (fp32, 16 rows per block).
__global__ __launch_bounds__(256) void k_main(const float* __restrict__ x,
                                              const float* __restrict__ W,
                                              const unsigned short* __restrict__ xhi,
                                              const unsigned short* __restrict__ xlo,
                                              float* __restrict__ S,
                                              uint32* __restrict__ hist1,
                                              float* __restrict__ h) {
    extern __shared__ char smem[];
    unsigned short* Ahi = (unsigned short*)(smem + SM_AHI);
    unsigned short* Alo = (unsigned short*)(smem + SM_ALO);
    unsigned short* Bhi = (unsigned short*)(smem + SM_BHI);
    unsigned short* Blo = (unsigned short*)(smem + SM_BLO);
    uint32*         hs  = (uint32*)(smem + SM_HS);
    float*          ts  = (float*)smem;   // [64][68] transpose buf, aliases Ahi/Alo
    int bid = blockIdx.x;
    int t = threadIdx.x;

    if (bid >= NTRI) {   // ---- h = X*W path ----
        int r0 = (bid - NTRI) * 16;
        int row = t >> 4, fg = t & 15;
        float acc[8];
        #pragma unroll
        for (int e = 0; e < 8; ++e) acc[e] = 0.f;
        for (int k = 0; k < FF; ++k) {
            float xr = x[(size_t)(r0 + row) * FF + k];
            float4 w0 = *(const float4*)&W[k * FF + fg * 8];
            float4 w1 = *(const float4*)&W[k * FF + fg * 8 + 4];
            acc[0] += xr * w0.x; acc[1] += xr * w0.y;
            acc[2] += xr * w0.z; acc[3] += xr * w0.w;
            acc[4] += xr * w1.x; acc[5] += xr * w1.y;
            acc[6] += xr * w1.z; acc[7] += xr * w1.w;
        }
        float4 o0 = {acc[0], acc[1], acc[2], acc[3]};
        float4 o1 = {acc[4], acc[5], acc[6], acc[7]};
        *(float4*)&h[(size_t)(r0 + row) * FF + fg * 8] = o0;
        *(float4*)&h[(size_t)(r0 + row) * FF + fg * 8 + 4] = o1;
        return;
    }

    // ---- sim path: triangular tile map ----
    int ti = 0, rem = bid;
    while (rem >= 32 - ti) { rem -= 32 - ti; ++ti; }
    int tj = ti + rem;
    bool diag = (ti == tj);
    int i0 = ti * 64, j0 = tj * 64;

    for (int i = t; i < NB; i += 256) hs[i] = 0;
    #pragma unroll
    for (int u = 0; u < 4; ++u) {
        int id = u * 256 + t;           // 1024 chunks per array (64 rows x 16)
        int r = id >> 4, c = id & 15;
        int sl = (c ^ (r & 7)) * 8;     // swizzled elem offset
        *(uint4*)&Ahi[r * 128 + sl] = *(const uint4*)&xhi[(size_t)(i0 + r) * FF + c * 8];
        *(uint4*)&Alo[r * 128 + sl] = *(const uint4*)&xlo[(size_t)(i0 + r) * FF + c * 8];
        if (!diag) {
            *(uint4*)&Bhi[r * 128 + sl] = *(const uint4*)&xhi[(size_t)(j0 + r) * FF + c * 8];
            *(uint4*)&Blo[r * 128 + sl] = *(const uint4*)&xlo[(size_t)(j0 + r) * FF + c * 8];
        }
    }
    __syncthreads();
    const unsigned short* Bh_r = diag ? Ahi : Bhi;
    const unsigned short* Bl_r = diag ? Alo : Blo;

    int wid = t >> 6, l = t & 63;
    int wy = wid >> 1, wx = wid & 1;
    int lr = l & 15, lg = l >> 4;
    f32x4 acc1[2][2], acc2[2][2];
    #pragma unroll
    for (int m = 0; m < 2; ++m)
        #pragma unroll
        for (int n = 0; n < 2; ++n) {
            acc1[m][n] = (f32x4){0.f, 0.f, 0.f, 0.f};
            acc2[m][n] = (f32x4){0.f, 0.f, 0.f, 0.f};
        }

    #pragma unroll
    for (int kk = 0; kk < 4; ++kk) {
        f16x8 ah[2], al[2], bh[2], bl[2];
        int chunk = kk * 4 + lg;
        #pragma unroll
        for (int m = 0; m < 2; ++m) {
            int row = wy * 32 + m * 16 + lr;
            int off = row * 128 + ((chunk ^ (row & 7)) * 8);
            ah[m] = *(f16x8*)&Ahi[off];
            al[m] = *(f16x8*)&Alo[off];
        }
        #pragma unroll
        for (int n = 0; n < 2; ++n) {
            int row = wx * 32 + n * 16 + lr;
            int off = row * 128 + ((chunk ^ (row & 7)) * 8);
            bh[n] = *(const f16x8*)&Bh_r[off];
            bl[n] = *(const f16x8*)&Bl_r[off];
        }
        #pragma unroll
        for (int m = 0; m < 2; ++m)
            #pragma unroll
            for (int n = 0; n < 2; ++n) {
                acc1[m][n] = __builtin_amdgcn_mfma_f32_16x16x32_f16(ah[m], bh[n], acc1[m][n], 0, 0, 0);
                acc2[m][n] = __builtin_amdgcn_mfma_f32_16x16x32_f16(ah[m], bl[n], acc2[m][n], 0, 0, 0);
                acc2[m][n] = __builtin_amdgcn_mfma_f32_16x16x32_f16(al[m], bh[n], acc2[m][n], 0, 0, 0);
            }
    }

    // C-write (col=lane&15, row=(lane>>4)*4+reg) + fused hist (weight 2 offdiag)
    uint32 hw = diag ? 1u : 2u;
    #pragma unroll
    for (int m = 0; m < 2; ++m) {
        #pragma unroll
        for (int n = 0; n < 2; ++n) {
            #pragma unroll
            for (int r = 0; r < 4; ++r) {
                int gi = i0 + wy * 32 + m * 16 + lg * 4 + r;
                int gj = j0 + wx * 32 + n * 16 + lr;
                float v = acc1[m][n][r] + acc2[m][n][r] * LO_UNSCALE;
                if (gi == gj) v -= 1.0f;          // subtract eye (diag tiles only)
                S[(size_t)gi * NN + gj] = v;
                atomicAdd(&hs[bin_of(v, LO1, INV1)], hw);
            }
        }
    }

    if (!diag) {   // mirror tile (tj,ti) via LDS transpose (ts aliases A-frags)
        __syncthreads();   // all waves done reading Ahi/Alo
        #pragma unroll
        for (int m = 0; m < 2; ++m)
            #pragma unroll
            for (int n = 0; n < 2; ++n)
                #pragma unroll
                for (int r = 0; r < 4; ++r) {
                    int li = wy * 32 + m * 16 + lg * 4 + r;   // local row (i)
                    int lj = wx * 32 + n * 16 + lr;           // local col (j)
                    ts[lj * 68 + li] = acc1[m][n][r] + acc2[m][n][r] * LO_UNSCALE;
                }
        __syncthreads();
        #pragma unroll
        for (int u = 0; u < 4; ++u) {
            int id = u * 256 + t;
            int a = id >> 4;           // local j (row of mirror tile)
            int b4 = (id & 15) * 4;    // local i
            float4 o = *(float4*)&ts[a * 68 + b4];
            *(float4*)&S[(size_t)(j0 + a) * NN + i0 + b4] = o;
        }
    }
    __syncthreads();
    uint32* hcopy = &hist1[(uint32)(bid & (NCOPY1 - 1)) * NB];
    for (int i = t; i < NB; i += 256) {
        uint32 v = hs[i];
        if (v) atomicAdd(&hcopy[i], v);
    }
}

// merge hist1 shards (1024 threads for MLP), find bin of K-th largest
__global__ __launch_bounds__(1024) void k_scan1(const uint32* __restrict__ hist1,
                                                uint32* __restrict__ scal) {
    __shared__ uint32 sh[NB];
    __shared__ uint32 csum[256];
    int t = threadIdx.x;
    for (int bin = t; bin < NB; bin += 1024) {
        uint32 s = 0;
        #pragma unroll
        for (int cp = 0; cp < NCOPY1; ++cp) s += hist1[cp * NB + bin];
        sh[bin] = s;
    }
    __syncthreads();
    if (t < 256) {
        uint32 s = 0;
        #pragma unroll
        for (int u = 0; u < 8; ++u) s += sh[t * 8 + u];
        csum[t] = s;
    }
    __syncthreads();
    if (t == 0) {
        uint32 K = KEEPK, cum = 0;
        int cb = 255;
        for (; cb > 0; --cb) {
            if (cum + csum[cb] >= K) break;
            cum += csum[cb];
        }
        int b;
        for (b = cb * 8 + 7; b > cb * 8; --b) {
            if (cum + sh[b] >= K) break;
            cum += sh[b];
        }
        scal[0] = (uint32)b;      // B1
        scal[1] = K - cum;        // K2
    }
}

// fused: level-2 histogram of bin B1 (unsharded) + gather ALL bin-B1 candidates
// + column sums of values strictly ABOVE bin B1 in registers (exclusive columns).
__global__ __launch_bounds__(256) void k_h2c(const float4* __restrict__ S4,
                                             uint32* __restrict__ hist2,
                                             float* __restrict__ candV,
                                             uint32* __restrict__ candF,
                                             float* __restrict__ csumG,
                                             uint32* __restrict__ scal) {
    __shared__ uint32 hs[NB];        // 8 KB level-2 hist
    __shared__ float  cs2[4][256];   // 4 KB  per-rowgroup column sums
    __shared__ float  bvv[LBUF];     // 8 KB
    __shared__ uint32 bff[LBUF];     // 8 KB
    __shared__ uint32 bcnt, gbase;
    int t = threadIdx.x;
    int cw = blockIdx.x & 7;         // column window: 256 cols
    int rg = blockIdx.x >> 3;        // row group: 32 rows (64 groups)
    for (int i = t; i < NB; i += 256) hs[i] = 0;
    if (t == 0) bcnt = 0;
    __syncthreads();
    int B1 = (int)scal[0];
    float lo2 = LO1 + (float)B1 * BINW1;
    int rown = t >> 6;               // 0..3
    int c64 = t & 63;                // float4-group within window
    int colbase = cw * 256 + c64 * 4;
    float creg[4] = {0.f, 0.f, 0.f, 0.f};
    #pragma unroll
    for (int it = 0; it < 8; ++it) {
        int row = rg * 32 + it * 4 + rown;
        float4 v = S4[(size_t)row * (NN / 4) + cw * 64 + c64];
        #pragma unroll
        for (int e = 0; e < 4; ++e) {
            float xv = (&v.x)[e];
            int b1 = bin_of(xv, LO1, INV1);
            if (b1 > B1) {
                creg[e] += xv;
            } else if (b1 == B1) {
                atomicAdd(&hs[bin_of(xv, lo2, INV2)], 1u);
                uint32 p = atomicAdd(&bcnt, 1u);
                uint32 flat = (uint32)row * (uint32)NN + (uint32)(colbase + e);
                if (p < LBUF) { bvv[p] = xv; bff[p] = flat; }
                else {  // overflow safety (statistically unreachable)
                    uint32 g = atomicAdd(&scal[5], 1u);
                    if (g < CAND_CAP) { candV[g] = xv; candF[g] = flat; }
                }
            }
        }
    }
    #pragma unroll
    for (int e = 0; e < 4; ++e) cs2[rown][c64 * 4 + e] = creg[e];
    __syncthreads();
    {   // thread t owns window-column t; 4 shards
        float s = cs2[0][t] + cs2[1][t] + cs2[2][t] + cs2[3][t];
        uint32 shard = (uint32)(blockIdx.x & (CSHARDS - 1));
        if (s != 0.f) atomicAdd(&csumG[shard * NN + cw * 256 + t], s);
    }
    uint32 n = bcnt > LBUF ? LBUF : bcnt;
    if (t == 0) gbase = atomicAdd(&scal[5], n);
    __syncthreads();
    uint32 gb = gbase;
    for (uint32 i = t; i < n; i += 256u) {
        uint32 g = gb + i;
        if (g < CAND_CAP) { candV[g] = bvv[i]; candF[g] = bff[i]; }
    }
    for (int i = t; i < NB; i += 256) {
        uint32 v = hs[i];
        if (v) atomicAdd(&hist2[i], v);
    }
}

// level-2 scan (hist2 unsharded: 8 KB read) -> B2, need
__global__ __launch_bounds__(256) void k_scan2(const uint32* __restrict__ hist2,
                                               uint32* __restrict__ scal) {
    __shared__ uint32 sh[NB];
    __shared__ uint32 csum[256];
    int t = threadIdx.x;
    uint32 tot = 0;
    #pragma unroll
    for (int u = 0; u < 8; ++u) {
        uint32 s = hist2[t * 8 + u];
        sh[t * 8 + u] = s; tot += s;
    }
    csum[t] = tot;
    __syncthreads();
    if (t == 0) {
        uint32 K = scal[1], cum = 0;
        int cb = 255;
        for (; cb > 0; --cb) {
            if (cum + csum[cb] >= K) break;
            cum += csum[cb];
        }
        int b;
        for (b = cb * 8 + 7; b > cb * 8; --b) {
            if (cum + sh[b] >= K) break;
            cum += sh[b];
        }
        scal[2] = (uint32)b;      // B2
        scal[3] = K - cum;        // need within B2
    }
}

// parallel filter of B1-candidates to bin B2 (LDS-staged, one atomic per block)
__global__ __launch_bounds__(256) void k_filt(const float* __restrict__ candV,
                                              const uint32* __restrict__ candF,
                                              float* __restrict__ c2V,
                                              uint32* __restrict__ c2F,
                                              uint32* __restrict__ scal) {
    __shared__ float  fv[1024];
    __shared__ uint32 ff[1024];
    __shared__ uint32 fcnt, fbase;
    int t = threadIdx.x;
    if (t == 0) fcnt = 0;
    __syncthreads();
    uint32 cnt = scal[5];
    if (cnt > CAND_CAP) cnt = CAND_CAP;
    int B1 = (int)scal[0], B2 = (int)scal[2];
    float lo2 = LO1 + (float)B1 * BINW1;
    for (uint32 i = blockIdx.x * 256u + t; i < cnt; i += gridDim.x * 256u) {
        float v = candV[i];
        if (bin_of(v, lo2, INV2) == B2) {
            uint32 p = atomicAdd(&fcnt, 1u);
            if (p < 1024u) { fv[p] = v; ff[p] = candF[i]; }
            else {  // overflow safety
                uint32 g = atomicAdd(&scal[8], 1u);
                if (g < C2_CAP) { c2V[g] = v; c2F[g] = candF[i]; }
            }
        }
    }
    __syncthreads();
    uint32 n = fcnt > 1024u ? 1024u : fcnt;
    if (t == 0) fbase = atomicAdd(&scal[8], n);
    __syncthreads();
    uint32 fb = fbase;
    for (uint32 i = t; i < n; i += 256u) {
        uint32 g = fb + i;
        if (g < C2_CAP) { c2V[g] = fv[i]; c2F[g] = ff[i]; }
    }
}

// exact tau + tie cutoff from the tiny filtered list (desc value, asc flat idx)
__global__ __launch_bounds__(256) void k_pick(const float* __restrict__ c2V,
                                              const uint32* __restrict__ c2F,
                                              uint32* __restrict__ scal) {
    __shared__ float  sv[C2_CAP];
    __shared__ uint32 sf[C2_CAP];
    int t = threadIdx.x;
    uint32 c2 = scal[8];
    if (c2 > C2_CAP) c2 = C2_CAP;
    for (uint32 i = t; i < c2; i += 256u) { sv[i] = c2V[i]; sf[i] = c2F[i]; }
    __syncthreads();
    if (t == 0) {
        uint32 need = scal[3];
        if (need > c2) need = c2;
        if (c2 == 0) { scal[6] = __float_as_uint(3.0e38f); scal[7] = 0u; return; }
        if (need == 0) need = 1;
        for (uint32 s = 0; s < need; ++s) {
            uint32 best = s;
            for (uint32 q = s + 1; q < c2; ++q) {
                if (sv[q] > sv[best] || (sv[q] == sv[best] && sf[q] < sf[best])) best = q;
            }
            float tv = sv[s]; sv[s] = sv[best]; sv[best] = tv;
            uint32 tf = sf[s]; sf[s] = sf[best]; sf[best] = tf;
        }
        scal[6] = __float_as_uint(sv[need - 1]);   // tau
        scal[7] = sf[need - 1];                    // cutoff (flat idx of last tie kept)
    }
}

// deg[j] = merge colsum shards (edges above bin B1, provably > tau);
// degc[j] += selected B1-bin candidates (global atomics; ~18k over 2048 addrs).
__global__ __launch_bounds__(256) void k_degsum(const float* __restrict__ csumG,
                                                const float* __restrict__ candV,
                                                const uint32* __restrict__ candF,
                                                const uint32* __restrict__ scal,
                                                float* __restrict__ deg,
                                                float* __restrict__ degc) {
    int tid = blockIdx.x * 256 + threadIdx.x;   // 64 blocks x 256 = 16384
    if (tid < NN) {
        float s = 0.f;
        #pragma unroll
        for (int cp = 0; cp < CSHARDS; ++cp) s += csumG[cp * NN + tid];
        deg[tid] = s;
    }
    uint32 cnt = scal[5];
    if (cnt > CAND_CAP) cnt = CAND_CAP;
    float tau = __uint_as_float(scal[6]);
    uint32 cutoff = scal[7];
    for (uint32 i = (uint32)tid; i < cnt; i += 16384u) {
        float v = candV[i];
        uint32 flat = candF[i];
        if (v > tau || (v == tau && flat <= cutoff))
            atomicAdd(&degc[flat & (NN - 1)], v);
    }
}

// part[p][j][f] = sum_{i in chunk p} sel(i,j)*S[i][j]*dinv[i]*h[i][f] via bf16 MFMA.
__global__ __launch_bounds__(256) void k_agg(const float* __restrict__ S,
                                             const float* __restrict__ h,
                                             const float* __restrict__ deg,
                                             const float* __restrict__ degc,
                                             const uint32* __restrict__ scal,
                                             float* __restrict__ part) {
    __shared__ unsigned short Aw[64 * 64];    // 8 KB, [j][i] swizzled
    __shared__ unsigned short Bh[128 * 64];   // 16 KB, [f][i] swizzled
    int t = threadIdx.x;
    int j0 = blockIdx.x * 64;
    int p = blockIdx.y;
    int ibase = p * (NN / NPART);
    float tau = __uint_as_float(scal[6]);
    uint32 cutoff = scal[7];
    int wid = t >> 6, l = t & 63;
    int wy = wid >> 1, wx = wid & 1;
    int lr = l & 15, lg = l >> 4;

    f32x4 acc[2][4];
    #pragma unroll
    for (int m = 0; m < 2; ++m)
        #pragma unroll
        for (int n = 0; n < 4; ++n) acc[m][n] = (f32x4){0.f, 0.f, 0.f, 0.f};

    for (int cc = 0; cc < (NN / NPART) / 64; ++cc) {
        int ib = ibase + cc * 64;
        __syncthreads();
        // stage A: masked S row-reads -> bf16
        #pragma unroll
        for (int u = 0; u < 2; ++u) {
            int id = u * 256 + t;
            int r = id >> 3, c = id & 7;
            int gj = j0 + r;
            unsigned short w8[8];
            #pragma unroll
            for (int q = 0; q < 2; ++q) {
                float4 v = *(const float4*)&S[(size_t)gj * NN + ib + c * 8 + q * 4];
                #pragma unroll
                for (int e = 0; e < 4; ++e) {
                    int gi = ib + c * 8 + q * 4 + e;
                    float vv = (&v.x)[e];
                    uint32 flat = (uint32)gi * (uint32)NN + (uint32)gj;
                    bool sel = (vv > tau) || (vv == tau && flat <= cutoff);
                    w8[q * 4 + e] = f2bf(sel ? vv : 0.f);
                }
            }
            *(uint4*)&Aw[r * 64 + ((c ^ (r & 7)) * 8)] = pack8(w8);
        }
        // stage B: transpose dinv-scaled h -> [f][i] bf16, swizzled
        {
            int i = t & 63, fh = (t >> 6) * 32;
            int gi = ib + i;
            float di = rsqrtf(deg[gi] + degc[gi] + 1.0f);
            #pragma unroll
            for (int q = 0; q < 8; ++q) {
                int f = fh + q * 4;
                float4 hv = *(const float4*)&h[(size_t)gi * FF + f];
                #pragma unroll
                for (int e = 0; e < 4; ++e) {
                    int fr = f + e;
                    Bh[fr * 64 + (((i >> 3) ^ (fr & 7)) * 8 + (i & 7))] =
                        f2bf((&hv.x)[e] * di);
                }
            }
        }
        __syncthreads();
        #pragma unroll
        for (int kk = 0; kk < 2; ++kk) {
            bf16x8 a[2], b[4];
            int chunk = kk * 4 + lg;
            #pragma unroll
            for (int m = 0; m < 2; ++m) {
                int row = wy * 32 + m * 16 + lr;
                a[m] = *(bf16x8*)&Aw[row * 64 + ((chunk ^ (row & 7)) * 8)];
            }
            #pragma unroll
            for (int n = 0; n < 4; ++n) {
                int row = wx * 64 + n * 16 + lr;
                b[n] = *(bf16x8*)&Bh[row * 64 + ((chunk ^ (row & 7)) * 8)];
            }
            #pragma unroll
            for (int m = 0; m < 2; ++m)
                #pragma unroll
                for (int n = 0; n < 4; ++n)
                    acc[m][n] = __builtin_amdgcn_mfma_f32_16x16x32_bf16(a[m], b[n], acc[m][n], 0, 0, 0);
        }
    }
    #pragma unroll
    for (int m = 0; m < 2; ++m)
        #pragma unroll
        for (int n = 0; n < 4; ++n)
            #pragma unroll
            for (int r = 0; r < 4; ++r) {
                int gj = j0 + wy * 32 + m * 16 + lg * 4 + r;
                int gf = wx * 64 + n * 16 + lr;
                part[((size_t)p * NN + gj) * FF + gf] = acc[m][n][r];
            }
}

// out[j][f] = b[f] + dj*(dj*h[j][f] + sum_p part[p][j][f]), dj = rsqrt(deg+degc+1)
__global__ __launch_bounds__(256) void k_reduce(const float* __restrict__ part,
                                                const float* __restrict__ h,
                                                const float* __restrict__ deg,
                                                const float* __restrict__ degc,
                                                const float* __restrict__ bvec,
                                                float* __restrict__ out) {
    int idx4 = blockIdx.x * 256 + threadIdx.x;   // 65536 float4s
    int j = idx4 >> 5;
    int f4 = (idx4 & 31) * 4;
    size_t off = (size_t)j * FF + f4;
    float4 s = *(const float4*)&part[off];
    #pragma unroll
    for (int p = 1; p < NPART; ++p) {
        float4 v = *(const float4*)&part[(size_t)p * NN * FF + off];
        s.x += v.x; s.y += v.y; s.z += v.z; s.w += v.w;
    }
    float dj = rsqrtf(deg[j] + degc[j] + 1.0f);
    float4 hv = *(const float4*)&h[off];
    float4 bv = *(const float4*)&bvec[f4];
    float4 o;
    o.x = bv.x + dj * (dj * hv.x + s.x);
    o.y = bv.y + dj * (dj * hv.y + s.y);
    o.z = bv.z + dj * (dj * hv.z + s.z);
    o.w = bv.w + dj * (dj * hv.w + s.w);
    *(float4*)&out[off] = o;
}

extern "C" void kernel_launch(void* const* d_in, const int* in_sizes, int n_in,
                              void* d_out, int out_size, void* d_ws, size_t ws_size,
                              hipStream_t stream) {
    const float* x = (const float*)d_in[0];   // [1,2048,128]
    const float* W = (const float*)d_in[1];   // [128,128]
    const float* b = (const float*)d_in[2];   // [128]
    float* out = (float*)d_out;

    if (ws_size < WS_NEEDED) return;  // insufficient scratch: fail visibly

    char* ws = (char*)d_ws;
    float*          deg   = (float*)(ws + OFF_DEG);
    float*          degc  = (float*)(ws + OFF_DEGC);
    uint32*         scal  = (uint32*)(ws + OFF_SCAL);
    uint32*         hist1 = (uint32*)(ws + OFF_HIST1);
    uint32*         hist2 = (uint32*)(ws + OFF_HIST2);
    float*          csumG = (float*)(ws + OFF_CSUM);
    float*          candV = (float*)(ws + OFF_CANDV);
    uint32*         candF = (uint32*)(ws + OFF_CANDF);
    float*          c2V   = (float*)(ws + OFF_C2V);
    uint32*         c2F   = (uint32*)(ws + OFF_C2F);
    unsigned short* xhi   = (unsigned short*)(ws + OFF_XHI);
    unsigned short* xlo   = (unsigned short*)(ws + OFF_XLO);
    float*          h     = (float*)(ws + OFF_H);
    float*          S     = (float*)(ws + OFF_S);
    float*          part  = (float*)(ws + OFF_PART);

    k_prep<<<128, 256, 0, stream>>>(x, xhi, xlo, (float4*)ws);
    k_main<<<NTRI + 128, 256, SM_TOTAL, stream>>>(x, W, xhi, xlo, S, hist1, h);
    k_scan1<<<1, 1024, 0, stream>>>(hist1, scal);
    k_h2c<<<512, 256, 0, stream>>>((const float4*)S, hist2, candV, candF, csumG, scal);
    k_scan2<<<1, 256, 0, stream>>>(hist2, scal);
    k_filt<<<64, 256, 0, stream>>>(candV, candF, c2V, c2F, scal);
    k_pick<<<1, 256, 0, stream>>>(c2V, c2F, scal);
    k_degsum<<<64, 256, 0, stream>>>(csumG, candV, candF, scal, deg, degc);
    k_agg<<<dim3(32, NPART), 256, 0, stream>>>(S, h, deg, degc, scal, part);
    k_reduce<<<256, 256, 0, stream>>>(part, h, deg, degc, b, out);
}

// Round 14
// 100.326 us; speedup vs baseline: 1.0651x; 1.0651x over previous
//
#include <hip/hip_runtime.h>

typedef unsigned int uint32;
typedef __attribute__((ext_vector_type(8))) _Float16 f16x8;
typedef __attribute__((ext_vector_type(8))) short bf16x8;
typedef __attribute__((ext_vector_type(4))) float f32x4;

#define NN 2048
#define FF 128
#define KEEPK 1258291u      // int(0.3 * 2048 * 2048)
#define NB 2048             // histogram bins per level
#define NCOPY1 16           // hist1 shards
#define CSHARDS 4           // colsum shards
#define LO1 (-4.0f)
#define BINW1 0.0625f       // 2^-4, exact
#define INV1 16.0f
#define INV2 32768.0f       // 2048 / BINW1 = 2^15, exact
#define CAND_CAP 131072u    // B1-bin population ~37k expected; 3.6x margin
#define LBUF 2048u          // per-block LDS candidate staging (k_h2c)
#define C2_CAP 4096u        // B2-filtered candidate capacity
#define NPART 8             // i-chunks for atomic-free aggregation
#define LO_SCALE 2048.0f    // 2^11: keep fp16 lo-part in normal range
#define LO_UNSCALE 4.8828125e-4f  // 2^-11

// workspace layout (bytes)  [ws_size = 256 MiB]
#define OFF_DEG    (0u)                 // float[2048]
#define OFF_DEGC   (8u*1024u)           // float[2048]
#define OFF_SCAL   (16u*1024u)          // uint[64]: 0=B1 1=K2 2=B2 3=need 5=c1 6=tau 7=cutoff 8=c2
#define OFF_HIST1  (17u*1024u)          // uint[16][2048] = 128K
#define OFF_HIST2  (145u*1024u)         // uint[2048] = 8K (unsharded)
#define OFF_CSUM   (153u*1024u)         // float[4][2048] = 32K
#define ZERO_BYTES (185u*1024u)         // region zeroed by k_prep
#define ZERO_F4    (11840u)             // ZERO_BYTES / 16
#define OFF_CANDV  (185u*1024u)         // float[131072] = 512K
#define OFF_CANDF  (697u*1024u)         // uint[131072]  = 512K
#define OFF_C2V    (1209u*1024u)        // float[4096] = 16K
#define OFF_C2F    (1225u*1024u)        // uint[4096]  = 16K
#define OFF_XHI    (1241u*1024u)        // fp16 hi(x) = 512K
#define OFF_XLO    (1753u*1024u)        // fp16 lo(x)*2048 = 512K
#define OFF_H      (2265u*1024u)        // float h = 1 MB
#define OFF_S      (3289u*1024u)        // float[2048*2048] = 16 MB
#define OFF_PART   (OFF_S + (uint32)NN*NN*4u)   // 8 MB
#define WS_NEEDED  ((size_t)OFF_PART + (size_t)NPART*NN*FF*4u)

__device__ __forceinline__ int bin_of(float v, float lo, float inv) {
    int b = (int)floorf((v - lo) * inv);
    return b < 0 ? 0 : (b > NB - 1 ? NB - 1 : b);
}

__device__ __forceinline__ unsigned short f2bf(float f) {   // round-to-nearest-even
    uint32 u = __float_as_uint(f);
    u += 0x7fffu + ((u >> 16) & 1u);
    return (unsigned short)(u >> 16);
}

__device__ __forceinline__ void split16(float v, unsigned short& hi, unsigned short& lo) {
    union { _Float16 f; unsigned short u; } a, b;
    a.f = (_Float16)v;
    float back = (float)a.f;
    b.f = (_Float16)((v - back) * LO_SCALE);
    hi = a.u; lo = b.u;
}

__device__ __forceinline__ uint4 pack8(const unsigned short* w) {  // 8 u16 -> uint4
    uint4 p;
    p.x = (uint32)w[0] | ((uint32)w[1] << 16);
    p.y = (uint32)w[2] | ((uint32)w[3] << 16);
    p.z = (uint32)w[4] | ((uint32)w[5] << 16);
    p.w = (uint32)w[6] | ((uint32)w[7] << 16);
    return p;
}

// one-shot split of x into fp16 hi/lo + fused zeroing of the accumulator region
__global__ __launch_bounds__(256) void k_prep(const float* __restrict__ x,
                                              unsigned short* __restrict__ xhi,
                                              unsigned short* __restrict__ xlo,
                                              float4* __restrict__ zbase) {
    int id = blockIdx.x * 256 + threadIdx.x;   // 32768 threads x 8 elems
    if ((uint32)id < ZERO_F4) zbase[id] = (float4){0.f, 0.f, 0.f, 0.f};
    float4 a0 = *(const float4*)&x[(size_t)id * 8];
    float4 a1 = *(const float4*)&x[(size_t)id * 8 + 4];
    unsigned short h8[8], l8[8];
    #pragma unroll
    for (int e = 0; e < 4; ++e) {
        split16((&a0.x)[e], h8[e], l8[e]);
        split16((&a1.x)[e], h8[4 + e], l8[4 + e]);
    }
    *(uint4*)&xhi[(size_t)id * 8] = pack8(h8);
    *(uint4*)&xlo[(size_t)id * 8] = pack8(l8);
}

// blocks [0,1024): S = X*X^T - I (split-fp16 MFMA, fp32-accurate) + sharded hist1
// (2 LDS hist copies to halve same-bin atomic serialization).
// blocks [1024,1152): h = X*W (fp32, 16 rows per block).
__global__ __launch_bounds__(256) void k_main(const float* __restrict__ x,
                                              const float* __restrict__ W,
                                              const unsigned short* __restrict__ xhi,
                                              const unsigned short* __restrict__ xlo,
                                              float* __restrict__ S,
                                              uint32* __restrict__ hist1,
                                              float* __restrict__ h) {
    __shared__ unsigned short Ahi[64 * 128];  // 16 KB each
    __shared__ unsigned short Alo[64 * 128];
    __shared__ unsigned short Bhi[64 * 128];
    __shared__ unsigned short Blo[64 * 128];
    __shared__ uint32 hs[2][NB];              // 16 KB (2 copies)
    int bid = blockIdx.x;
    int t = threadIdx.x;

    if (bid >= 1024) {   // ---- h = X*W path ----
        int r0 = (bid - 1024) * 16;
        int row = t >> 4, fg = t & 15;
        float acc[8];
        #pragma unroll
        for (int e = 0; e < 8; ++e) acc[e] = 0.f;
        for (int k = 0; k < FF; ++k) {
            float xr = x[(size_t)(r0 + row) * FF + k];
            float4 w0 = *(const float4*)&W[k * FF + fg * 8];
            float4 w1 = *(const float4*)&W[k * FF + fg * 8 + 4];
            acc[0] += xr * w0.x; acc[1] += xr * w0.y;
            acc[2] += xr * w0.z; acc[3] += xr * w0.w;
            acc[4] += xr * w1.x; acc[5] += xr * w1.y;
            acc[6] += xr * w1.z; acc[7] += xr * w1.w;
        }
        float4 o0 = {acc[0], acc[1], acc[2], acc[3]};
        float4 o1 = {acc[4], acc[5], acc[6], acc[7]};
        *(float4*)&h[(size_t)(r0 + row) * FF + fg * 8] = o0;
        *(float4*)&h[(size_t)(r0 + row) * FF + fg * 8 + 4] = o1;
        return;
    }

    // ---- sim path ----
    for (int i = t; i < NB; i += 256) { hs[0][i] = 0; hs[1][i] = 0; }
    int i0 = (bid >> 5) * 64, j0 = (bid & 31) * 64;
    #pragma unroll
    for (int u = 0; u < 4; ++u) {
        int id = u * 256 + t;           // 1024 chunks per array (64 rows x 16)
        int r = id >> 4, c = id & 15;
        int sl = (c ^ (r & 7)) * 8;     // swizzled elem offset
        *(uint4*)&Ahi[r * 128 + sl] = *(const uint4*)&xhi[(size_t)(i0 + r) * FF + c * 8];
        *(uint4*)&Alo[r * 128 + sl] = *(const uint4*)&xlo[(size_t)(i0 + r) * FF + c * 8];
        *(uint4*)&Bhi[r * 128 + sl] = *(const uint4*)&xhi[(size_t)(j0 + r) * FF + c * 8];
        *(uint4*)&Blo[r * 128 + sl] = *(const uint4*)&xlo[(size_t)(j0 + r) * FF + c * 8];
    }
    __syncthreads();

    int wid = t >> 6, l = t & 63;
    int wy = wid >> 1, wx = wid & 1;
    int lr = l & 15, lg = l >> 4;
    f32x4 acc1[2][2], acc2[2][2];
    #pragma unroll
    for (int m = 0; m < 2; ++m)
        #pragma unroll
        for (int n = 0; n < 2; ++n) {
            acc1[m][n] = (f32x4){0.f, 0.f, 0.f, 0.f};
            acc2[m][n] = (f32x4){0.f, 0.f, 0.f, 0.f};
        }

    #pragma unroll
    for (int kk = 0; kk < 4; ++kk) {
        f16x8 ah[2], al[2], bh[2], bl[2];
        int chunk = kk * 4 + lg;
        #pragma unroll
        for (int m = 0; m < 2; ++m) {
            int row = wy * 32 + m * 16 + lr;
            int off = row * 128 + ((chunk ^ (row & 7)) * 8);
            ah[m] = *(f16x8*)&Ahi[off];
            al[m] = *(f16x8*)&Alo[off];
        }
        #pragma unroll
        for (int n = 0; n < 2; ++n) {
            int row = wx * 32 + n * 16 + lr;
            int off = row * 128 + ((chunk ^ (row & 7)) * 8);
            bh[n] = *(f16x8*)&Bhi[off];
            bl[n] = *(f16x8*)&Blo[off];
        }
        #pragma unroll
        for (int m = 0; m < 2; ++m)
            #pragma unroll
            for (int n = 0; n < 2; ++n) {
                acc1[m][n] = __builtin_amdgcn_mfma_f32_16x16x32_f16(ah[m], bh[n], acc1[m][n], 0, 0, 0);
                acc2[m][n] = __builtin_amdgcn_mfma_f32_16x16x32_f16(ah[m], bl[n], acc2[m][n], 0, 0, 0);
                acc2[m][n] = __builtin_amdgcn_mfma_f32_16x16x32_f16(al[m], bh[n], acc2[m][n], 0, 0, 0);
            }
    }

    // C-write (col=lane&15, row=(lane>>4)*4+reg) + fused hist (copy by t&1)
    uint32* hrow = hs[t & 1];
    #pragma unroll
    for (int m = 0; m < 2; ++m) {
        #pragma unroll
        for (int n = 0; n < 2; ++n) {
            #pragma unroll
            for (int r = 0; r < 4; ++r) {
                int gi = i0 + wy * 32 + m * 16 + lg * 4 + r;
                int gj = j0 + wx * 32 + n * 16 + lr;
                float v = acc1[m][n][r] + acc2[m][n][r] * LO_UNSCALE;
                if (gi == gj) v -= 1.0f;          // subtract eye
                S[(size_t)gi * NN + gj] = v;
                atomicAdd(&hrow[bin_of(v, LO1, INV1)], 1u);
            }
        }
    }
    __syncthreads();
    uint32* hcopy = &hist1[(uint32)(bid & (NCOPY1 - 1)) * NB];
    for (int i = t; i < NB; i += 256) {
        uint32 v = hs[0][i] + hs[1][i];
        if (v) atomicAdd(&hcopy[i], v);
    }
}

// merge hist1 shards (1024 threads for MLP), find bin of K-th largest
__global__ __launch_bounds__(1024) void k_scan1(const uint32* __restrict__ hist1,
                                                uint32* __restrict__ scal) {
    __shared__ uint32 sh[NB];
    __shared__ uint32 csum[256];
    int t = threadIdx.x;
    for (int bin = t; bin < NB; bin += 1024) {
        uint32 s = 0;
        #pragma unroll
        for (int cp = 0; cp < NCOPY1; ++cp) s += hist1[cp * NB + bin];
        sh[bin] = s;
    }
    __syncthreads();
    if (t < 256) {
        uint32 s = 0;
        #pragma unroll
        for (int u = 0; u < 8; ++u) s += sh[t * 8 + u];
        csum[t] = s;
    }
    __syncthreads();
    if (t == 0) {
        uint32 K = KEEPK, cum = 0;
        int cb = 255;
        for (; cb > 0; --cb) {
            if (cum + csum[cb] >= K) break;
            cum += csum[cb];
        }
        int b;
        for (b = cb * 8 + 7; b > cb * 8; --b) {
            if (cum + sh[b] >= K) break;
            cum += sh[b];
        }
        scal[0] = (uint32)b;      // B1
        scal[1] = K - cum;        // K2
    }
}

// fused: level-2 histogram of bin B1 (unsharded) + gather ALL bin-B1 candidates
// + column sums of values strictly ABOVE bin B1 in registers (exclusive columns).
__global__ __launch_bounds__(256) void k_h2c(const float4* __restrict__ S4,
                                             uint32* __restrict__ hist2,
                                             float* __restrict__ candV,
                                             uint32* __restrict__ candF,
                                             float* __restrict__ csumG,
                                             uint32* __restrict__ scal) {
    __shared__ uint32 hs[NB];        // 8 KB level-2 hist
    __shared__ float  cs2[4][256];   // 4 KB  per-rowgroup column sums
    __shared__ float  bvv[LBUF];     // 8 KB
    __shared__ uint32 bff[LBUF];     // 8 KB
    __shared__ uint32 bcnt, gbase;
    int t = threadIdx.x;
    int cw = blockIdx.x & 7;         // column window: 256 cols
    int rg = blockIdx.x >> 3;        // row group: 32 rows (64 groups)
    for (int i = t; i < NB; i += 256) hs[i] = 0;
    if (t == 0) bcnt = 0;
    __syncthreads();
    int B1 = (int)scal[0];
    float lo2 = LO1 + (float)B1 * BINW1;
    int rown = t >> 6;               // 0..3
    int c64 = t & 63;                // float4-group within window
    int colbase = cw * 256 + c64 * 4;
    float creg[4] = {0.f, 0.f, 0.f, 0.f};
    #pragma unroll
    for (int it = 0; it < 8; ++it) {
        int row = rg * 32 + it * 4 + rown;
        float4 v = S4[(size_t)row * (NN / 4) + cw * 64 + c64];
        #pragma unroll
        for (int e = 0; e < 4; ++e) {
            float xv = (&v.x)[e];
            int b1 = bin_of(xv, LO1, INV1);
            if (b1 > B1) {
                creg[e] += xv;
            } else if (b1 == B1) {
                atomicAdd(&hs[bin_of(xv, lo2, INV2)], 1u);
                uint32 p = atomicAdd(&bcnt, 1u);
                uint32 flat = (uint32)row * (uint32)NN + (uint32)(colbase + e);
                if (p < LBUF) { bvv[p] = xv; bff[p] = flat; }
                else {  // overflow safety (statistically unreachable)
                    uint32 g = atomicAdd(&scal[5], 1u);
                    if (g < CAND_CAP) { candV[g] = xv; candF[g] = flat; }
                }
            }
        }
    }
    #pragma unroll
    for (int e = 0; e < 4; ++e) cs2[rown][c64 * 4 + e] = creg[e];
    __syncthreads();
    {   // thread t owns window-column t; 4 shards
        float s = cs2[0][t] + cs2[1][t] + cs2[2][t] + cs2[3][t];
        uint32 shard = (uint32)(blockIdx.x & (CSHARDS - 1));
        if (s != 0.f) atomicAdd(&csumG[shard * NN + cw * 256 + t], s);
    }
    uint32 n = bcnt > LBUF ? LBUF : bcnt;
    if (t == 0) gbase = atomicAdd(&scal[5], n);
    __syncthreads();
    uint32 gb = gbase;
    for (uint32 i = t; i < n; i += 256u) {
        uint32 g = gb + i;
        if (g < CAND_CAP) { candV[g] = bvv[i]; candF[g] = bff[i]; }
    }
    for (int i = t; i < NB; i += 256) {
        uint32 v = hs[i];
        if (v) atomicAdd(&hist2[i], v);
    }
}

// fused scan2+filter: each block redundantly scans hist2 (8 KB, L2) -> B2/need,
// then filters B1-candidates to bin B2 (LDS-staged, one global atomic per block).
__global__ __launch_bounds__(256) void k_filt(const uint32* __restrict__ hist2,
                                              const float* __restrict__ candV,
                                              const uint32* __restrict__ candF,
                                              float* __restrict__ c2V,
                                              uint32* __restrict__ c2F,
                                              uint32* __restrict__ scal) {
    __shared__ uint32 sh[NB];        // 8 KB
    __shared__ uint32 csum[256];
    __shared__ float  fv[1024];
    __shared__ uint32 ff[1024];
    __shared__ uint32 fcnt, fbase, sB2;
    int t = threadIdx.x;
    if (t == 0) fcnt = 0;
    // inline level-2 scan (same in every block; deterministic)
    uint32 tot = 0;
    #pragma unroll
    for (int u = 0; u < 8; ++u) {
        uint32 s = hist2[t * 8 + u];
        sh[t * 8 + u] = s; tot += s;
    }
    csum[t] = tot;
    __syncthreads();
    if (t == 0) {
        uint32 K = scal[1], cum = 0;
        int cb = 255;
        for (; cb > 0; --cb) {
            if (cum + csum[cb] >= K) break;
            cum += csum[cb];
        }
        int b;
        for (b = cb * 8 + 7; b > cb * 8; --b) {
            if (cum + sh[b] >= K) break;
            cum += sh[b];
        }
        sB2 = (uint32)b;
        if (blockIdx.x == 0) {
            scal[2] = (uint32)b;     // B2 (for reference)
            scal[3] = K - cum;       // need within B2 (k_pick reads this)
        }
    }
    __syncthreads();
    uint32 cnt = scal[5];
    if (cnt > CAND_CAP) cnt = CAND_CAP;
    int B1 = (int)scal[0], B2 = (int)sB2;
    float lo2 = LO1 + (float)B1 * BINW1;
    for (uint32 i = blockIdx.x * 256u + t; i < cnt; i += gridDim.x * 256u) {
        float v = candV[i];
        if (bin_of(v, lo2, INV2) == B2) {
            uint32 p = atomicAdd(&fcnt, 1u);
            if (p < 1024u) { fv[p] = v; ff[p] = candF[i]; }
            else {  // overflow safety
                uint32 g = atomicAdd(&scal[8], 1u);
                if (g < C2_CAP) { c2V[g] = v; c2F[g] = candF[i]; }
            }
        }
    }
    __syncthreads();
    uint32 n = fcnt > 1024u ? 1024u : fcnt;
    if (t == 0) fbase = atomicAdd(&scal[8], n);
    __syncthreads();
    uint32 fb = fbase;
    for (uint32 i = t; i < n; i += 256u) {
        uint32 g = fb + i;
        if (g < C2_CAP) { c2V[g] = fv[i]; c2F[g] = ff[i]; }
    }
}

// exact tau + tie cutoff from the tiny filtered list (desc value, asc flat idx)
__global__ __launch_bounds__(256) void k_pick(const float* __restrict__ c2V,
                                              const uint32* __restrict__ c2F,
                                              uint32* __restrict__ scal) {
    __shared__ float  sv[C2_CAP];
    __shared__ uint32 sf[C2_CAP];
    int t = threadIdx.x;
    uint32 c2 = scal[8];
    if (c2 > C2_CAP) c2 = C2_CAP;
    for (uint32 i = t; i < c2; i += 256u) { sv[i] = c2V[i]; sf[i] = c2F[i]; }
    __syncthreads();
    if (t == 0) {
        uint32 need = scal[3];
        if (need > c2) need = c2;
        if (c2 == 0) { scal[6] = __float_as_uint(3.0e38f); scal[7] = 0u; return; }
        if (need == 0) need = 1;
        for (uint32 s = 0; s < need; ++s) {
            uint32 best = s;
            for (uint32 q = s + 1; q < c2; ++q) {
                if (sv[q] > sv[best] || (sv[q] == sv[best] && sf[q] < sf[best])) best = q;
            }
            float tv = sv[s]; sv[s] = sv[best]; sv[best] = tv;
            uint32 tf = sf[s]; sf[s] = sf[best]; sf[best] = tf;
        }
        scal[6] = __float_as_uint(sv[need - 1]);   // tau
        scal[7] = sf[need - 1];                    // cutoff (flat idx of last tie kept)
    }
}

// deg[j] = merge colsum shards (edges above bin B1, provably > tau);
// degc[j] += selected B1-bin candidates (global atomics; ~18k over 2048 addrs).
__global__ __launch_bounds__(256) void k_degsum(const float* __restrict__ csumG,
                                                const float* __restrict__ candV,
                                                const uint32* __restrict__ candF,
                                                const uint32* __restrict__ scal,
                                                float* __restrict__ deg,
                                                float* __restrict__ degc) {
    int tid = blockIdx.x * 256 + threadIdx.x;   // 64 blocks x 256 = 16384
    if (tid < NN) {
        float s = 0.f;
        #pragma unroll
        for (int cp = 0; cp < CSHARDS; ++cp) s += csumG[cp * NN + tid];
        deg[tid] = s;
    }
    uint32 cnt = scal[5];
    if (cnt > CAND_CAP) cnt = CAND_CAP;
    float tau = __uint_as_float(scal[6]);
    uint32 cutoff = scal[7];
    for (uint32 i = (uint32)tid; i < cnt; i += 16384u) {
        float v = candV[i];
        uint32 flat = candF[i];
        if (v > tau || (v == tau && flat <= cutoff))
            atomicAdd(&degc[flat & (NN - 1)], v);
    }
}

// part[p][j][f] = sum_{i in chunk p} sel(i,j)*S[i][j]*dinv[i]*h[i][f] via bf16 MFMA.
__global__ __launch_bounds__(256) void k_agg(const float* __restrict__ S,
                                             const float* __restrict__ h,
                                             const float* __restrict__ deg,
                                             const float* __restrict__ degc,
                                             const uint32* __restrict__ scal,
                                             float* __restrict__ part) {
    __shared__ unsigned short Aw[64 * 64];    // 8 KB, [j][i] swizzled
    __shared__ unsigned short Bh[128 * 64];   // 16 KB, [f][i] swizzled
    int t = threadIdx.x;
    int j0 = blockIdx.x * 64;
    int p = blockIdx.y;
    int ibase = p * (NN / NPART);
    float tau = __uint_as_float(scal[6]);
    uint32 cutoff = scal[7];
    int wid = t >> 6, l = t & 63;
    int wy = wid >> 1, wx = wid & 1;
    int lr = l & 15, lg = l >> 4;

    f32x4 acc[2][4];
    #pragma unroll
    for (int m = 0; m < 2; ++m)
        #pragma unroll
        for (int n = 0; n < 4; ++n) acc[m][n] = (f32x4){0.f, 0.f, 0.f, 0.f};

    for (int cc = 0; cc < (NN / NPART) / 64; ++cc) {
        int ib = ibase + cc * 64;
        __syncthreads();
        // stage A: masked S row-reads -> bf16
        #pragma unroll
        for (int u = 0; u < 2; ++u) {
            int id = u * 256 + t;
            int r = id >> 3, c = id & 7;
            int gj = j0 + r;
            unsigned short w8[8];
            #pragma unroll
            for (int q = 0; q < 2; ++q) {
                float4 v = *(const float4*)&S[(size_t)gj * NN + ib + c * 8 + q * 4];
                #pragma unroll
                for (int e = 0; e < 4; ++e) {
                    int gi = ib + c * 8 + q * 4 + e;
                    float vv = (&v.x)[e];
                    uint32 flat = (uint32)gi * (uint32)NN + (uint32)gj;
                    bool sel = (vv > tau) || (vv == tau && flat <= cutoff);
                    w8[q * 4 + e] = f2bf(sel ? vv : 0.f);
                }
            }
            *(uint4*)&Aw[r * 64 + ((c ^ (r & 7)) * 8)] = pack8(w8);
        }
        // stage B: transpose dinv-scaled h -> [f][i] bf16, swizzled
        {
            int i = t & 63, fh = (t >> 6) * 32;
            int gi = ib + i;
            float di = rsqrtf(deg[gi] + degc[gi] + 1.0f);
            #pragma unroll
            for (int q = 0; q < 8; ++q) {
                int f = fh + q * 4;
                float4 hv = *(const float4*)&h[(size_t)gi * FF + f];
                #pragma unroll
                for (int e = 0; e < 4; ++e) {
                    int fr = f + e;
                    Bh[fr * 64 + (((i >> 3) ^ (fr & 7)) * 8 + (i & 7))] =
                        f2bf((&hv.x)[e] * di);
                }
            }
        }
        __syncthreads();
        #pragma unroll
        for (int kk = 0; kk < 2; ++kk) {
            bf16x8 a[2], b[4];
            int chunk = kk * 4 + lg;
            #pragma unroll
            for (int m = 0; m < 2; ++m) {
                int row = wy * 32 + m * 16 + lr;
                a[m] = *(bf16x8*)&Aw[row * 64 + ((chunk ^ (row & 7)) * 8)];
            }
            #pragma unroll
            for (int n = 0; n < 4; ++n) {
                int row = wx * 64 + n * 16 + lr;
                b[n] = *(bf16x8*)&Bh[row * 64 + ((chunk ^ (row & 7)) * 8)];
            }
            #pragma unroll
            for (int m = 0; m < 2; ++m)
                #pragma unroll
                for (int n = 0; n < 4; ++n)
                    acc[m][n] = __builtin_amdgcn_mfma_f32_16x16x32_bf16(a[m], b[n], acc[m][n], 0, 0, 0);
        }
    }
    #pragma unroll
    for (int m = 0; m < 2; ++m)
        #pragma unroll
        for (int n = 0; n < 4; ++n)
            #pragma unroll
            for (int r = 0; r < 4; ++r) {
                int gj = j0 + wy * 32 + m * 16 + lg * 4 + r;
                int gf = wx * 64 + n * 16 + lr;
                part[((size_t)p * NN + gj) * FF + gf] = acc[m][n][r];
            }
}

// out[j][f] = b[f] + dj*(dj*h[j][f] + sum_p part[p][j][f]), dj = rsqrt(deg+degc+1)
__global__ __launch_bounds__(256) void k_reduce(const float* __restrict__ part,
                                                const float* __restrict__ h,
                                                const float* __restrict__ deg,
                                                const float* __restrict__ degc,
                                                const float* __restrict__ bvec,
                                                float* __restrict__ out) {
    int idx4 = blockIdx.x * 256 + threadIdx.x;   // 65536 float4s
    int j = idx4 >> 5;
    int f4 = (idx4 & 31) * 4;
    size_t off = (size_t)j * FF + f4;
    float4 s = *(const float4*)&part[off];
    #pragma unroll
    for (int p = 1; p < NPART; ++p) {
        float4 v = *(const float4*)&part[(size_t)p * NN * FF + off];
        s.x += v.x; s.y += v.y; s.z += v.z; s.w += v.w;
    }
    float dj = rsqrtf(deg[j] + degc[j] + 1.0f);
    float4 hv = *(const float4*)&h[off];
    float4 bv = *(const float4*)&bvec[f4];
    float4 o;
    o.x = bv.x + dj * (dj * hv.x + s.x);
    o.y = bv.y + dj * (dj * hv.y + s.y);
    o.z = bv.z + dj * (dj * hv.z + s.z);
    o.w = bv.w + dj * (dj * hv.w + s.w);
    *(float4*)&out[off] = o;
}

extern "C" void kernel_launch(void* const* d_in, const int* in_sizes, int n_in,
                              void* d_out, int out_size, void* d_ws, size_t ws_size,
                              hipStream_t stream) {
    const float* x = (const float*)d_in[0];   // [1,2048,128]
    const float* W = (const float*)d_in[1];   // [128,128]
    const float* b = (const float*)d_in[2];   // [128]
    float* out = (float*)d_out;

    if (ws_size < WS_NEEDED) return;  // insufficient scratch: fail visibly

    char* ws = (char*)d_ws;
    float*          deg   = (float*)(ws + OFF_DEG);
    float*          degc  = (float*)(ws + OFF_DEGC);
    uint32*         scal  = (uint32*)(ws + OFF_SCAL);
    uint32*         hist1 = (uint32*)(ws + OFF_HIST1);
    uint32*         hist2 = (uint32*)(ws + OFF_HIST2);
    float*          csumG = (float*)(ws + OFF_CSUM);
    float*          candV = (float*)(ws + OFF_CANDV);
    uint32*         candF = (uint32*)(ws + OFF_CANDF);
    float*          c2V   = (float*)(ws + OFF_C2V);
    uint32*         c2F   = (uint32*)(ws + OFF_C2F);
    unsigned short* xhi   = (unsigned short*)(ws + OFF_XHI);
    unsigned short* xlo   = (unsigned short*)(ws + OFF_XLO);
    float*          h     = (float*)(ws + OFF_H);
    float*          S     = (float*)(ws + OFF_S);
    float*          part  = (float*)(ws + OFF_PART);

    k_prep<<<128, 256, 0, stream>>>(x, xhi, xlo, (float4*)ws);
    k_main<<<1152, 256, 0, stream>>>(x, W, xhi, xlo, S, hist1, h);
    k_scan1<<<1, 1024, 0, stream>>>(hist1, scal);
    k_h2c<<<512, 256, 0, stream>>>((const float4*)S, hist2, candV, candF, csumG, scal);
    k_filt<<<64, 256, 0, stream>>>(hist2, candV, candF, c2V, c2F, scal);
    k_pick<<<1, 256, 0, stream>>>(c2V, c2F, scal);
    k_degsum<<<64, 256, 0, stream>>>(csumG, candV, candF, scal, deg, degc);
    k_agg<<<dim3(32, NPART), 256, 0, stream>>>(S, h, deg, degc, scal, part);
    k_reduce<<<256, 256, 0, stream>>>(part, h, deg, degc, b, out);
}

// Round 15
// 96.865 us; speedup vs baseline: 1.1032x; 1.0357x over previous
//
#include <hip/hip_runtime.h>

typedef unsigned int uint32;
typedef __attribute__((ext_vector_type(8))) _Float16 f16x8;
typedef __attribute__((ext_vector_type(8))) short bf16x8;
typedef __attribute__((ext_vector_type(4))) float f32x4;

#define NN 2048
#define FF 128
#define KEEPK 1258291u      // int(0.3 * 2048 * 2048)
#define NB 2048             // histogram bins per level
#define NCOPY1 16           // hist1 shards
#define CSHARDS 4           // colsum shards
#define LO1 (-4.0f)
#define BINW1 0.0625f       // 2^-4, exact
#define INV1 16.0f
#define INV2 32768.0f       // 2048 / BINW1 = 2^15, exact
#define CAND_CAP 131072u    // B1-bin population ~37k expected; 3.6x margin
#define LBUF 2048u          // per-block LDS candidate staging (k_h2c)
#define C2_CAP 4096u        // B2-filtered candidate capacity
#define NPART 8             // i-chunks for atomic-free aggregation
#define LO_SCALE 2048.0f    // 2^11: keep fp16 lo-part in normal range
#define LO_UNSCALE 4.8828125e-4f  // 2^-11

// workspace layout (bytes)  [ws_size = 256 MiB]
#define OFF_DEG    (0u)                 // float[2048]
#define OFF_DEGC   (8u*1024u)           // float[2048]
#define OFF_SCAL   (16u*1024u)          // uint[64]: 0=B1 1=K2 2=B2 3=need 5=c1 6=tau 7=cutoff 8=c2
#define OFF_HIST1  (17u*1024u)          // uint[16][2048] = 128K
#define OFF_HIST2  (145u*1024u)         // uint[2048] = 8K (unsharded)
#define OFF_CSUM   (153u*1024u)         // float[4][2048] = 32K
#define ZERO_BYTES (185u*1024u)         // region zeroed by k_prep
#define ZERO_F4    (11840u)             // ZERO_BYTES / 16
#define OFF_CANDV  (185u*1024u)         // float[131072] = 512K
#define OFF_CANDF  (697u*1024u)         // uint[131072]  = 512K
#define OFF_C2V    (1209u*1024u)        // float[4096] = 16K
#define OFF_C2F    (1225u*1024u)        // uint[4096]  = 16K
#define OFF_XHI    (1241u*1024u)        // fp16 hi(x) = 512K
#define OFF_XLO    (1753u*1024u)        // fp16 lo(x)*2048 = 512K
#define OFF_H      (2265u*1024u)        // float h = 1 MB
#define OFF_S      (3289u*1024u)        // float[2048*2048] = 16 MB
#define OFF_PART   (OFF_S + (uint32)NN*NN*4u)   // 8 MB
#define WS_NEEDED  ((size_t)OFF_PART + (size_t)NPART*NN*FF*4u)

__device__ __forceinline__ int bin_of(float v, float lo, float inv) {
    int b = (int)floorf((v - lo) * inv);
    return b < 0 ? 0 : (b > NB - 1 ? NB - 1 : b);
}

__device__ __forceinline__ unsigned short f2bf(float f) {   // round-to-nearest-even
    uint32 u = __float_as_uint(f);
    u += 0x7fffu + ((u >> 16) & 1u);
    return (unsigned short)(u >> 16);
}

__device__ __forceinline__ void split16(float v, unsigned short& hi, unsigned short& lo) {
    union { _Float16 f; unsigned short u; } a, b;
    a.f = (_Float16)v;
    float back = (float)a.f;
    b.f = (_Float16)((v - back) * LO_SCALE);
    hi = a.u; lo = b.u;
}

__device__ __forceinline__ uint4 pack8(const unsigned short* w) {  // 8 u16 -> uint4
    uint4 p;
    p.x = (uint32)w[0] | ((uint32)w[1] << 16);
    p.y = (uint32)w[2] | ((uint32)w[3] << 16);
    p.z = (uint32)w[4] | ((uint32)w[5] << 16);
    p.w = (uint32)w[6] | ((uint32)w[7] << 16);
    return p;
}

// one-shot split of x into fp16 hi/lo + fused zeroing of the accumulator region
__global__ __launch_bounds__(256) void k_prep(const float* __restrict__ x,
                                              unsigned short* __restrict__ xhi,
                                              unsigned short* __restrict__ xlo,
                                              float4* __restrict__ zbase) {
    int id = blockIdx.x * 256 + threadIdx.x;   // 32768 threads x 8 elems
    if ((uint32)id < ZERO_F4) zbase[id] = (float4){0.f, 0.f, 0.f, 0.f};
    float4 a0 = *(const float4*)&x[(size_t)id * 8];
    float4 a1 = *(const float4*)&x[(size_t)id * 8 + 4];
    unsigned short h8[8], l8[8];
    #pragma unroll
    for (int e = 0; e < 4; ++e) {
        split16((&a0.x)[e], h8[e], l8[e]);
        split16((&a1.x)[e], h8[4 + e], l8[4 + e]);
    }
    *(uint4*)&xhi[(size_t)id * 8] = pack8(h8);
    *(uint4*)&xlo[(size_t)id * 8] = pack8(l8);
}

// blocks [0,1024): S = X*X^T - I (split-fp16 MFMA, fp32-accurate) + sharded hist1
// (2 LDS hist copies to halve same-bin atomic serialization).
// blocks [1024,1152): h = X*W (fp32, 16 rows per block).
__global__ __launch_bounds__(256) void k_main(const float* __restrict__ x,
                                              const float* __restrict__ W,
                                              const unsigned short* __restrict__ xhi,
                                              const unsigned short* __restrict__ xlo,
                                              float* __restrict__ S,
                                              uint32* __restrict__ hist1,
                                              float* __restrict__ h) {
    __shared__ unsigned short Ahi[64 * 128];  // 16 KB each
    __shared__ unsigned short Alo[64 * 128];
    __shared__ unsigned short Bhi[64 * 128];
    __shared__ unsigned short Blo[64 * 128];
    __shared__ uint32 hs[2][NB];              // 16 KB (2 copies)
    int bid = blockIdx.x;
    int t = threadIdx.x;

    if (bid >= 1024) {   // ---- h = X*W path ----
        int r0 = (bid - 1024) * 16;
        int row = t >> 4, fg = t & 15;
        float acc[8];
        #pragma unroll
        for (int e = 0; e < 8; ++e) acc[e] = 0.f;
        for (int k = 0; k < FF; ++k) {
            float xr = x[(size_t)(r0 + row) * FF + k];
            float4 w0 = *(const float4*)&W[k * FF + fg * 8];
            float4 w1 = *(const float4*)&W[k * FF + fg * 8 + 4];
            acc[0] += xr * w0.x; acc[1] += xr * w0.y;
            acc[2] += xr * w0.z; acc[3] += xr * w0.w;
            acc[4] += xr * w1.x; acc[5] += xr * w1.y;
            acc[6] += xr * w1.z; acc[7] += xr * w1.w;
        }
        float4 o0 = {acc[0], acc[1], acc[2], acc[3]};
        float4 o1 = {acc[4], acc[5], acc[6], acc[7]};
        *(float4*)&h[(size_t)(r0 + row) * FF + fg * 8] = o0;
        *(float4*)&h[(size_t)(r0 + row) * FF + fg * 8 + 4] = o1;
        return;
    }

    // ---- sim path ----
    for (int i = t; i < NB; i += 256) { hs[0][i] = 0; hs[1][i] = 0; }
    int i0 = (bid >> 5) * 64, j0 = (bid & 31) * 64;
    #pragma unroll
    for (int u = 0; u < 4; ++u) {
        int id = u * 256 + t;           // 1024 chunks per array (64 rows x 16)
        int r = id >> 4, c = id & 15;
        int sl = (c ^ (r & 7)) * 8;     // swizzled elem offset
        *(uint4*)&Ahi[r * 128 + sl] = *(const uint4*)&xhi[(size_t)(i0 + r) * FF + c * 8];
        *(uint4*)&Alo[r * 128 + sl] = *(const uint4*)&xlo[(size_t)(i0 + r) * FF + c * 8];
        *(uint4*)&Bhi[r * 128 + sl] = *(const uint4*)&xhi[(size_t)(j0 + r) * FF + c * 8];
        *(uint4*)&Blo[r * 128 + sl] = *(const uint4*)&xlo[(size_t)(j0 + r) * FF + c * 8];
    }
    __syncthreads();

    int wid = t >> 6, l = t & 63;
    int wy = wid >> 1, wx = wid & 1;
    int lr = l & 15, lg = l >> 4;
    f32x4 acc1[2][2], acc2[2][2];
    #pragma unroll
    for (int m = 0; m < 2; ++m)
        #pragma unroll
        for (int n = 0; n < 2; ++n) {
            acc1[m][n] = (f32x4){0.f, 0.f, 0.f, 0.f};
            acc2[m][n] = (f32x4){0.f, 0.f, 0.f, 0.f};
        }

    #pragma unroll
    for (int kk = 0; kk < 4; ++kk) {
        f16x8 ah[2], al[2], bh[2], bl[2];
        int chunk = kk * 4 + lg;
        #pragma unroll
        for (int m = 0; m < 2; ++m) {
            int row = wy * 32 + m * 16 + lr;
            int off = row * 128 + ((chunk ^ (row & 7)) * 8);
            ah[m] = *(f16x8*)&Ahi[off];
            al[m] = *(f16x8*)&Alo[off];
        }
        #pragma unroll
        for (int n = 0; n < 2; ++n) {
            int row = wx * 32 + n * 16 + lr;
            int off = row * 128 + ((chunk ^ (row & 7)) * 8);
            bh[n] = *(f16x8*)&Bhi[off];
            bl[n] = *(f16x8*)&Blo[off];
        }
        #pragma unroll
        for (int m = 0; m < 2; ++m)
            #pragma unroll
            for (int n = 0; n < 2; ++n) {
                acc1[m][n] = __builtin_amdgcn_mfma_f32_16x16x32_f16(ah[m], bh[n], acc1[m][n], 0, 0, 0);
                acc2[m][n] = __builtin_amdgcn_mfma_f32_16x16x32_f16(ah[m], bl[n], acc2[m][n], 0, 0, 0);
                acc2[m][n] = __builtin_amdgcn_mfma_f32_16x16x32_f16(al[m], bh[n], acc2[m][n], 0, 0, 0);
            }
    }

    // C-write (col=lane&15, row=(lane>>4)*4+reg) + fused hist (copy by t&1)
    uint32* hrow = hs[t & 1];
    #pragma unroll
    for (int m = 0; m < 2; ++m) {
        #pragma unroll
        for (int n = 0; n < 2; ++n) {
            #pragma unroll
            for (int r = 0; r < 4; ++r) {
                int gi = i0 + wy * 32 + m * 16 + lg * 4 + r;
                int gj = j0 + wx * 32 + n * 16 + lr;
                float v = acc1[m][n][r] + acc2[m][n][r] * LO_UNSCALE;
                if (gi == gj) v -= 1.0f;          // subtract eye
                S[(size_t)gi * NN + gj] = v;
                atomicAdd(&hrow[bin_of(v, LO1, INV1)], 1u);
            }
        }
    }
    __syncthreads();
    uint32* hcopy = &hist1[(uint32)(bid & (NCOPY1 - 1)) * NB];
    for (int i = t; i < NB; i += 256) {
        uint32 v = hs[0][i] + hs[1][i];
        if (v) atomicAdd(&hcopy[i], v);
    }
}

// fused scan1 + level-2 histogram + candidate gather + colsum-above-B1.
// Phase 0 (every block, redundant & deterministic): merge hist1 shards -> B1, K2.
// Then: level-2 hist of bin B1 (unsharded) + gather ALL bin-B1 candidates
// (LDS staging, one global atomic per block) + column sums of values strictly
// ABOVE bin B1 in registers (each thread exclusively owns 4 columns).
__global__ __launch_bounds__(256) void k_h2c(const float4* __restrict__ S4,
                                             const uint32* __restrict__ hist1,
                                             uint32* __restrict__ hist2,
                                             float* __restrict__ candV,
                                             uint32* __restrict__ candF,
                                             float* __restrict__ csumG,
                                             uint32* __restrict__ scal) {
    __shared__ uint32 hs[NB];        // 8 KB: first merged hist1, then level-2 hist
    __shared__ uint32 csum[256];     // 1 KB
    __shared__ float  cs2[4][256];   // 4 KB  per-rowgroup column sums
    __shared__ float  bvv[LBUF];     // 8 KB
    __shared__ uint32 bff[LBUF];     // 8 KB
    __shared__ uint32 bcnt, gbase, sB1;
    int t = threadIdx.x;
    int cw = blockIdx.x & 7;         // column window: 256 cols
    int rg = blockIdx.x >> 3;        // row group: 32 rows (64 groups)

    // ---- phase 0: merge hist1 shards, scan for B1/K2 (redundant per block) ----
    {
        uint32 s8[8];
        #pragma unroll
        for (int u = 0; u < 8; ++u) s8[u] = 0;
        #pragma unroll
        for (int cp = 0; cp < NCOPY1; ++cp) {
            const uint4* hp = (const uint4*)&hist1[cp * NB + t * 8];
            uint4 a = hp[0], b = hp[1];
            s8[0] += a.x; s8[1] += a.y; s8[2] += a.z; s8[3] += a.w;
            s8[4] += b.x; s8[5] += b.y; s8[6] += b.z; s8[7] += b.w;
        }
        uint32 tot = 0;
        #pragma unroll
        for (int u = 0; u < 8; ++u) { hs[t * 8 + u] = s8[u]; tot += s8[u]; }
        csum[t] = tot;
    }
    if (t == 0) bcnt = 0;
    __syncthreads();
    if (t == 0) {
        uint32 K = KEEPK, cum = 0;
        int cb = 255;
        for (; cb > 0; --cb) {
            if (cum + csum[cb] >= K) break;
            cum += csum[cb];
        }
        int b;
        for (b = cb * 8 + 7; b > cb * 8; --b) {
            if (cum + hs[b] >= K) break;
            cum += hs[b];
        }
        sB1 = (uint32)b;
        scal[0] = (uint32)b;      // B1 (same value from every block)
        scal[1] = K - cum;        // K2 (same value from every block)
    }
    __syncthreads();
    int B1 = (int)sB1;
    // re-zero hs for the level-2 histogram
    for (int i = t; i < NB; i += 256) hs[i] = 0;
    __syncthreads();

    float lo2 = LO1 + (float)B1 * BINW1;
    int rown = t >> 6;               // 0..3
    int c64 = t & 63;                // float4-group within window
    int colbase = cw * 256 + c64 * 4;
    float creg[4] = {0.f, 0.f, 0.f, 0.f};
    #pragma unroll
    for (int it = 0; it < 8; ++it) {
        int row = rg * 32 + it * 4 + rown;
        float4 v = S4[(size_t)row * (NN / 4) + cw * 64 + c64];
        #pragma unroll
        for (int e = 0; e < 4; ++e) {
            float xv = (&v.x)[e];
            int b1 = bin_of(xv, LO1, INV1);
            if (b1 > B1) {
                creg[e] += xv;
            } else if (b1 == B1) {
                atomicAdd(&hs[bin_of(xv, lo2, INV2)], 1u);
                uint32 p = atomicAdd(&bcnt, 1u);
                uint32 flat = (uint32)row * (uint32)NN + (uint32)(colbase + e);
                if (p < LBUF) { bvv[p] = xv; bff[p] = flat; }
                else {  // overflow safety (statistically unreachable)
                    uint32 g = atomicAdd(&scal[5], 1u);
                    if (g < CAND_CAP) { candV[g] = xv; candF[g] = flat; }
                }
            }
        }
    }
    #pragma unroll
    for (int e = 0; e < 4; ++e) cs2[rown][c64 * 4 + e] = creg[e];
    __syncthreads();
    {   // thread t owns window-column t; 4 shards
        float s = cs2[0][t] + cs2[1][t] + cs2[2][t] + cs2[3][t];
        uint32 shard = (uint32)(blockIdx.x & (CSHARDS - 1));
        if (s != 0.f) atomicAdd(&csumG[shard * NN + cw * 256 + t], s);
    }
    uint32 n = bcnt > LBUF ? LBUF : bcnt;
    if (t == 0) gbase = atomicAdd(&scal[5], n);
    __syncthreads();
    uint32 gb = gbase;
    for (uint32 i = t; i < n; i += 256u) {
        uint32 g = gb + i;
        if (g < CAND_CAP) { candV[g] = bvv[i]; candF[g] = bff[i]; }
    }
    for (int i = t; i < NB; i += 256) {
        uint32 v = hs[i];
        if (v) atomicAdd(&hist2[i], v);
    }
}

// fused scan2+filter: each block redundantly scans hist2 (8 KB, L2) -> B2/need,
// then filters B1-candidates to bin B2 (LDS-staged, one global atomic per block).
__global__ __launch_bounds__(256) void k_filt(const uint32* __restrict__ hist2,
                                              const float* __restrict__ candV,
                                              const uint32* __restrict__ candF,
                                              float* __restrict__ c2V,
                                              uint32* __restrict__ c2F,
                                              uint32* __restrict__ scal) {
    __shared__ uint32 sh[NB];        // 8 KB
    __shared__ uint32 csum[256];
    __shared__ float  fv[1024];
    __shared__ uint32 ff[1024];
    __shared__ uint32 fcnt, fbase, sB2;
    int t = threadIdx.x;
    if (t == 0) fcnt = 0;
    // inline level-2 scan (same in every block; deterministic)
    uint32 tot = 0;
    #pragma unroll
    for (int u = 0; u < 8; ++u) {
        uint32 s = hist2[t * 8 + u];
        sh[t * 8 + u] = s; tot += s;
    }
    csum[t] = tot;
    __syncthreads();
    if (t == 0) {
        uint32 K = scal[1], cum = 0;
        int cb = 255;
        for (; cb > 0; --cb) {
            if (cum + csum[cb] >= K) break;
            cum += csum[cb];
        }
        int b;
        for (b = cb * 8 + 7; b > cb * 8; --b) {
            if (cum + sh[b] >= K) break;
            cum += sh[b];
        }
        sB2 = (uint32)b;
        if (blockIdx.x == 0) {
            scal[2] = (uint32)b;     // B2 (for reference)
            scal[3] = K - cum;       // need within B2 (k_pick reads this)
        }
    }
    __syncthreads();
    uint32 cnt = scal[5];
    if (cnt > CAND_CAP) cnt = CAND_CAP;
    int B1 = (int)scal[0], B2 = (int)sB2;
    float lo2 = LO1 + (float)B1 * BINW1;
    for (uint32 i = blockIdx.x * 256u + t; i < cnt; i += gridDim.x * 256u) {
        float v = candV[i];
        if (bin_of(v, lo2, INV2) == B2) {
            uint32 p = atomicAdd(&fcnt, 1u);
            if (p < 1024u) { fv[p] = v; ff[p] = candF[i]; }
            else {  // overflow safety
                uint32 g = atomicAdd(&scal[8], 1u);
                if (g < C2_CAP) { c2V[g] = v; c2F[g] = candF[i]; }
            }
        }
    }
    __syncthreads();
    uint32 n = fcnt > 1024u ? 1024u : fcnt;
    if (t == 0) fbase = atomicAdd(&scal[8], n);
    __syncthreads();
    uint32 fb = fbase;
    for (uint32 i = t; i < n; i += 256u) {
        uint32 g = fb + i;
        if (g < C2_CAP) { c2V[g] = fv[i]; c2F[g] = ff[i]; }
    }
}

// exact tau + tie cutoff from the tiny filtered list (desc value, asc flat idx)
__global__ __launch_bounds__(256) void k_pick(const float* __restrict__ c2V,
                                              const uint32* __restrict__ c2F,
                                              uint32* __restrict__ scal) {
    __shared__ float  sv[C2_CAP];
    __shared__ uint32 sf[C2_CAP];
    int t = threadIdx.x;
    uint32 c2 = scal[8];
    if (c2 > C2_CAP) c2 = C2_CAP;
    for (uint32 i = t; i < c2; i += 256u) { sv[i] = c2V[i]; sf[i] = c2F[i]; }
    __syncthreads();
    if (t == 0) {
        uint32 need = scal[3];
        if (need > c2) need = c2;
        if (c2 == 0) { scal[6] = __float_as_uint(3.0e38f); scal[7] = 0u; return; }
        if (need == 0) need = 1;
        for (uint32 s = 0; s < need; ++s) {
            uint32 best = s;
            for (uint32 q = s + 1; q < c2; ++q) {
                if (sv[q] > sv[best] || (sv[q] == sv[best] && sf[q] < sf[best])) best = q;
            }
            float tv = sv[s]; sv[s] = sv[best]; sv[best] = tv;
            uint32 tf = sf[s]; sf[s] = sf[best]; sf[best] = tf;
        }
        scal[6] = __float_as_uint(sv[need - 1]);   // tau
        scal[7] = sf[need - 1];                    // cutoff (flat idx of last tie kept)
    }
}

// deg[j] = merge colsum shards (edges above bin B1, provably > tau);
// degc[j] += selected B1-bin candidates (global atomics; ~18k over 2048 addrs).
__global__ __launch_bounds__(256) void k_degsum(const float* __restrict__ csumG,
                                                const float* __restrict__ candV,
                                                const uint32* __restrict__ candF,
                                                const uint32* __restrict__ scal,
                                                float* __restrict__ deg,
                                                float* __restrict__ degc) {
    int tid = blockIdx.x * 256 + threadIdx.x;   // 64 blocks x 256 = 16384
    if (tid < NN) {
        float s = 0.f;
        #pragma unroll
        for (int cp = 0; cp < CSHARDS; ++cp) s += csumG[cp * NN + tid];
        deg[tid] = s;
    }
    uint32 cnt = scal[5];
    if (cnt > CAND_CAP) cnt = CAND_CAP;
    float tau = __uint_as_float(scal[6]);
    uint32 cutoff = scal[7];
    for (uint32 i = (uint32)tid; i < cnt; i += 16384u) {
        float v = candV[i];
        uint32 flat = candF[i];
        if (v > tau || (v == tau && flat <= cutoff))
            atomicAdd(&degc[flat & (NN - 1)], v);
    }
}

// part[p][j][f] = sum_{i in chunk p} sel(i,j)*S[i][j]*dinv[i]*h[i][f] via bf16 MFMA.
__global__ __launch_bounds__(256) void k_agg(const float* __restrict__ S,
                                             const float* __restrict__ h,
                                             const float* __restrict__ deg,
                                             const float* __restrict__ degc,
                                             const uint32* __restrict__ scal,
                                             float* __restrict__ part) {
    __shared__ unsigned short Aw[64 * 64];    // 8 KB, [j][i] swizzled
    __shared__ unsigned short Bh[128 * 64];   // 16 KB, [f][i] swizzled
    int t = threadIdx.x;
    int j0 = blockIdx.x * 64;
    int p = blockIdx.y;
    int ibase = p * (NN / NPART);
    float tau = __uint_as_float(scal[6]);
    uint32 cutoff = scal[7];
    int wid = t >> 6, l = t & 63;
    int wy = wid >> 1, wx = wid & 1;
    int lr = l & 15, lg = l >> 4;

    f32x4 acc[2][4];
    #pragma unroll
    for (int m = 0; m < 2; ++m)
        #pragma unroll
        for (int n = 0; n < 4; ++n) acc[m][n] = (f32x4){0.f, 0.f, 0.f, 0.f};

    for (int cc = 0; cc < (NN / NPART) / 64; ++cc) {
        int ib = ibase + cc * 64;
        __syncthreads();
        // stage A: masked S row-reads -> bf16
        #pragma unroll
        for (int u = 0; u < 2; ++u) {
            int id = u * 256 + t;
            int r = id >> 3, c = id & 7;
            int gj = j0 + r;
            unsigned short w8[8];
            #pragma unroll
            for (int q = 0; q < 2; ++q) {
                float4 v = *(const float4*)&S[(size_t)gj * NN + ib + c * 8 + q * 4];
                #pragma unroll
                for (int e = 0; e < 4; ++e) {
                    int gi = ib + c * 8 + q * 4 + e;
                    float vv = (&v.x)[e];
                    uint32 flat = (uint32)gi * (uint32)NN + (uint32)gj;
                    bool sel = (vv > tau) || (vv == tau && flat <= cutoff);
                    w8[q * 4 + e] = f2bf(sel ? vv : 0.f);
                }
            }
            *(uint4*)&Aw[r * 64 + ((c ^ (r & 7)) * 8)] = pack8(w8);
        }
        // stage B: transpose dinv-scaled h -> [f][i] bf16, swizzled
        {
            int i = t & 63, fh = (t >> 6) * 32;
            int gi = ib + i;
            float di = rsqrtf(deg[gi] + degc[gi] + 1.0f);
            #pragma unroll
            for (int q = 0; q < 8; ++q) {
                int f = fh + q * 4;
                float4 hv = *(const float4*)&h[(size_t)gi * FF + f];
                #pragma unroll
                for (int e = 0; e < 4; ++e) {
                    int fr = f + e;
                    Bh[fr * 64 + (((i >> 3) ^ (fr & 7)) * 8 + (i & 7))] =
                        f2bf((&hv.x)[e] * di);
                }
            }
        }
        __syncthreads();
        #pragma unroll
        for (int kk = 0; kk < 2; ++kk) {
            bf16x8 a[2], b[4];
            int chunk = kk * 4 + lg;
            #pragma unroll
            for (int m = 0; m < 2; ++m) {
                int row = wy * 32 + m * 16 + lr;
                a[m] = *(bf16x8*)&Aw[row * 64 + ((chunk ^ (row & 7)) * 8)];
            }
            #pragma unroll
            for (int n = 0; n < 4; ++n) {
                int row = wx * 64 + n * 16 + lr;
                b[n] = *(bf16x8*)&Bh[row * 64 + ((chunk ^ (row & 7)) * 8)];
            }
            #pragma unroll
            for (int m = 0; m < 2; ++m)
                #pragma unroll
                for (int n = 0; n < 4; ++n)
                    acc[m][n] = __builtin_amdgcn_mfma_f32_16x16x32_bf16(a[m], b[n], acc[m][n], 0, 0, 0);
        }
    }
    #pragma unroll
    for (int m = 0; m < 2; ++m)
        #pragma unroll
        for (int n = 0; n < 4; ++n)
            #pragma unroll
            for (int r = 0; r < 4; ++r) {
                int gj = j0 + wy * 32 + m * 16 + lg * 4 + r;
                int gf = wx * 64 + n * 16 + lr;
                part[((size_t)p * NN + gj) * FF + gf] = acc[m][n][r];
            }
}

// out[j][f] = b[f] + dj*(dj*h[j][f] + sum_p part[p][j][f]), dj = rsqrt(deg+degc+1)
__global__ __launch_bounds__(256) void k_reduce(const float* __restrict__ part,
                                                const float* __restrict__ h,
                                                const float* __restrict__ deg,
                                                const float* __restrict__ degc,
                                                const float* __restrict__ bvec,
                                                float* __restrict__ out) {
    int idx4 = blockIdx.x * 256 + threadIdx.x;   // 65536 float4s
    int j = idx4 >> 5;
    int f4 = (idx4 & 31) * 4;
    size_t off = (size_t)j * FF + f4;
    float4 s = *(const float4*)&part[off];
    #pragma unroll
    for (int p = 1; p < NPART; ++p) {
        float4 v = *(const float4*)&part[(size_t)p * NN * FF + off];
        s.x += v.x; s.y += v.y; s.z += v.z; s.w += v.w;
    }
    float dj = rsqrtf(deg[j] + degc[j] + 1.0f);
    float4 hv = *(const float4*)&h[off];
    float4 bv = *(const float4*)&bvec[f4];
    float4 o;
    o.x = bv.x + dj * (dj * hv.x + s.x);
    o.y = bv.y + dj * (dj * hv.y + s.y);
    o.z = bv.z + dj * (dj * hv.z + s.z);
    o.w = bv.w + dj * (dj * hv.w + s.w);
    *(float4*)&out[off] = o;
}

extern "C" void kernel_launch(void* const* d_in, const int* in_sizes, int n_in,
                              void* d_out, int out_size, void* d_ws, size_t ws_size,
                              hipStream_t stream) {
    const float* x = (const float*)d_in[0];   // [1,2048,128]
    const float* W = (const float*)d_in[1];   // [128,128]
    const float* b = (const float*)d_in[2];   // [128]
    float* out = (float*)d_out;

    if (ws_size < WS_NEEDED) return;  // insufficient scratch: fail visibly

    char* ws = (char*)d_ws;
    float*          deg   = (float*)(ws + OFF_DEG);
    float*          degc  = (float*)(ws + OFF_DEGC);
    uint32*         scal  = (uint32*)(ws + OFF_SCAL);
    uint32*         hist1 = (uint32*)(ws + OFF_HIST1);
    uint32*         hist2 = (uint32*)(ws + OFF_HIST2);
    float*          csumG = (float*)(ws + OFF_CSUM);
    float*          candV = (float*)(ws + OFF_CANDV);
    uint32*         candF = (uint32*)(ws + OFF_CANDF);
    float*          c2V   = (float*)(ws + OFF_C2V);
    uint32*         c2F   = (uint32*)(ws + OFF_C2F);
    unsigned short* xhi   = (unsigned short*)(ws + OFF_XHI);
    unsigned short* xlo   = (unsigned short*)(ws + OFF_XLO);
    float*          h     = (float*)(ws + OFF_H);
    float*          S     = (float*)(ws + OFF_S);
    float*          part  = (float*)(ws + OFF_PART);

    k_prep<<<128, 256, 0, stream>>>(x, xhi, xlo, (float4*)ws);
    k_main<<<1152, 256, 0, stream>>>(x, W, xhi, xlo, S, hist1, h);
    k_h2c<<<512, 256, 0, stream>>>((const float4*)S, hist1, hist2, candV, candF, csumG, scal);
    k_filt<<<64, 256, 0, stream>>>(hist2, candV, candF, c2V, c2F, scal);
    k_pick<<<1, 256, 0, stream>>>(c2V, c2F, scal);
    k_degsum<<<64, 256, 0, stream>>>(csumG, candV, candF, scal, deg, degc);
    k_agg<<<dim3(32, NPART), 256, 0, stream>>>(S, h, deg, degc, scal, part);
    k_reduce<<<256, 256, 0, stream>>>(part, h, deg, degc, b, out);
}

// Round 16
// 91.088 us; speedup vs baseline: 1.1732x; 1.0634x over previous
//
#include <hip/hip_runtime.h>

typedef unsigned int uint32;
typedef __attribute__((ext_vector_type(8))) _Float16 f16x8;
typedef __attribute__((ext_vector_type(4))) _Float16 f16x4;
typedef __attribute__((ext_vector_type(8))) short bf16x8;
typedef __attribute__((ext_vector_type(4))) float f32x4;

#define NN 2048
#define FF 128
#define KEEPK 1258291u      // int(0.3 * 2048 * 2048)
#define NB 2048             // histogram bins per level
#define NCOPY1 16           // hist1 shards
#define CSHARDS 4           // colsum shards
#define LO1 (-4.0f)
#define BINW1 0.0625f       // 2^-4, exact
#define INV1 16.0f
#define INV2 32768.0f       // 2048 / BINW1 = 2^15, exact
#define CAND_CAP 131072u    // B1-bin population ~37k expected; 3.6x margin
#define LBUF 2048u          // per-block LDS candidate staging (k_h2c)
#define C2_CAP 4096u        // B2-filtered candidate capacity
#define NPART 16            // i-chunks for atomic-free aggregation (2 blocks/CU)
#define LO_SCALE 2048.0f    // 2^11: keep fp16 lo-part in normal range
#define LO_UNSCALE 4.8828125e-4f  // 2^-11

// workspace layout (bytes)  [ws_size = 256 MiB]
#define OFF_DEG    (0u)                 // float[2048]
#define OFF_DEGC   (8u*1024u)           // float[2048]
#define OFF_SCAL   (16u*1024u)          // uint[64]: 0=B1 1=K2 2=B2 3=need 5=c1 6=tau 7=cutoff 8=c2
#define OFF_HIST1  (17u*1024u)          // uint[16][2048] = 128K
#define OFF_HIST2  (145u*1024u)         // uint[2048] = 8K (unsharded)
#define OFF_CSUM   (153u*1024u)         // float[4][2048] = 32K
#define ZERO_BYTES (185u*1024u)         // region zeroed by k_prep
#define ZERO_F4    (11840u)             // ZERO_BYTES / 16
#define OFF_CANDV  (185u*1024u)         // float[131072] = 512K
#define OFF_CANDF  (697u*1024u)         // uint[131072]  = 512K
#define OFF_C2V    (1209u*1024u)        // float[4096] = 16K
#define OFF_C2F    (1225u*1024u)        // uint[4096]  = 16K
#define OFF_XHI    (1241u*1024u)        // fp16 hi(x) = 512K
#define OFF_XLO    (1753u*1024u)        // fp16 lo(x)*2048 = 512K
#define OFF_H      (2265u*1024u)        // float h = 1 MB
#define OFF_S      (3289u*1024u)        // float[2048*2048] = 16 MB
#define OFF_PART   (OFF_S + (uint32)NN*NN*4u)   // fp16[NPART][2048][128] = 8 MB
#define WS_NEEDED  ((size_t)OFF_PART + (size_t)NPART*NN*FF*2u)

__device__ __forceinline__ int bin_of(float v, float lo, float inv) {
    int b = (int)floorf((v - lo) * inv);
    return b < 0 ? 0 : (b > NB - 1 ? NB - 1 : b);
}

__device__ __forceinline__ unsigned short f2bf(float f) {   // round-to-nearest-even
    uint32 u = __float_as_uint(f);
    u += 0x7fffu + ((u >> 16) & 1u);
    return (unsigned short)(u >> 16);
}

__device__ __forceinline__ void split16(float v, unsigned short& hi, unsigned short& lo) {
    union { _Float16 f; unsigned short u; } a, b;
    a.f = (_Float16)v;
    float back = (float)a.f;
    b.f = (_Float16)((v - back) * LO_SCALE);
    hi = a.u; lo = b.u;
}

__device__ __forceinline__ uint4 pack8(const unsigned short* w) {  // 8 u16 -> uint4
    uint4 p;
    p.x = (uint32)w[0] | ((uint32)w[1] << 16);
    p.y = (uint32)w[2] | ((uint32)w[3] << 16);
    p.z = (uint32)w[4] | ((uint32)w[5] << 16);
    p.w = (uint32)w[6] | ((uint32)w[7] << 16);
    return p;
}

// one-shot split of x into fp16 hi/lo + fused zeroing of the accumulator region
__global__ __launch_bounds__(256) void k_prep(const float* __restrict__ x,
                                              unsigned short* __restrict__ xhi,
                                              unsigned short* __restrict__ xlo,
                                              float4* __restrict__ zbase) {
    int id = blockIdx.x * 256 + threadIdx.x;   // 32768 threads x 8 elems
    if ((uint32)id < ZERO_F4) zbase[id] = (float4){0.f, 0.f, 0.f, 0.f};
    float4 a0 = *(const float4*)&x[(size_t)id * 8];
    float4 a1 = *(const float4*)&x[(size_t)id * 8 + 4];
    unsigned short h8[8], l8[8];
    #pragma unroll
    for (int e = 0; e < 4; ++e) {
        split16((&a0.x)[e], h8[e], l8[e]);
        split16((&a1.x)[e], h8[4 + e], l8[4 + e]);
    }
    *(uint4*)&xhi[(size_t)id * 8] = pack8(h8);
    *(uint4*)&xlo[(size_t)id * 8] = pack8(l8);
}

// blocks [0,1024): S = X*X^T - I (split-fp16 MFMA, fp32-accurate) + sharded hist1
// (2 LDS hist copies to halve same-bin atomic serialization).
// blocks [1024,1152): h = X*W (fp32, 16 rows per block).
__global__ __launch_bounds__(256) void k_main(const float* __restrict__ x,
                                              const float* __restrict__ W,
                                              const unsigned short* __restrict__ xhi,
                                              const unsigned short* __restrict__ xlo,
                                              float* __restrict__ S,
                                              uint32* __restrict__ hist1,
                                              float* __restrict__ h) {
    __shared__ unsigned short Ahi[64 * 128];  // 16 KB each
    __shared__ unsigned short Alo[64 * 128];
    __shared__ unsigned short Bhi[64 * 128];
    __shared__ unsigned short Blo[64 * 128];
    __shared__ uint32 hs[2][NB];              // 16 KB (2 copies)
    int bid = blockIdx.x;
    int t = threadIdx.x;

    if (bid >= 1024) {   // ---- h = X*W path ----
        int r0 = (bid - 1024) * 16;
        int row = t >> 4, fg = t & 15;
        float acc[8];
        #pragma unroll
        for (int e = 0; e < 8; ++e) acc[e] = 0.f;
        for (int k = 0; k < FF; ++k) {
            float xr = x[(size_t)(r0 + row) * FF + k];
            float4 w0 = *(const float4*)&W[k * FF + fg * 8];
            float4 w1 = *(const float4*)&W[k * FF + fg * 8 + 4];
            acc[0] += xr * w0.x; acc[1] += xr * w0.y;
            acc[2] += xr * w0.z; acc[3] += xr * w0.w;
            acc[4] += xr * w1.x; acc[5] += xr * w1.y;
            acc[6] += xr * w1.z; acc[7] += xr * w1.w;
        }
        float4 o0 = {acc[0], acc[1], acc[2], acc[3]};
        float4 o1 = {acc[4], acc[5], acc[6], acc[7]};
        *(float4*)&h[(size_t)(r0 + row) * FF + fg * 8] = o0;
        *(float4*)&h[(size_t)(r0 + row) * FF + fg * 8 + 4] = o1;
        return;
    }

    // ---- sim path ----
    for (int i = t; i < NB; i += 256) { hs[0][i] = 0; hs[1][i] = 0; }
    int i0 = (bid >> 5) * 64, j0 = (bid & 31) * 64;
    #pragma unroll
    for (int u = 0; u < 4; ++u) {
        int id = u * 256 + t;           // 1024 chunks per array (64 rows x 16)
        int r = id >> 4, c = id & 15;
        int sl = (c ^ (r & 7)) * 8;     // swizzled elem offset
        *(uint4*)&Ahi[r * 128 + sl] = *(const uint4*)&xhi[(size_t)(i0 + r) * FF + c * 8];
        *(uint4*)&Alo[r * 128 + sl] = *(const uint4*)&xlo[(size_t)(i0 + r) * FF + c * 8];
        *(uint4*)&Bhi[r * 128 + sl] = *(const uint4*)&xhi[(size_t)(j0 + r) * FF + c * 8];
        *(uint4*)&Blo[r * 128 + sl] = *(const uint4*)&xlo[(size_t)(j0 + r) * FF + c * 8];
    }
    __syncthreads();

    int wid = t >> 6, l = t & 63;
    int wy = wid >> 1, wx = wid & 1;
    int lr = l & 15, lg = l >> 4;
    f32x4 acc1[2][2], acc2[2][2];
    #pragma unroll
    for (int m = 0; m < 2; ++m)
        #pragma unroll
        for (int n = 0; n < 2; ++n) {
            acc1[m][n] = (f32x4){0.f, 0.f, 0.f, 0.f};
            acc2[m][n] = (f32x4){0.f, 0.f, 0.f, 0.f};
        }

    #pragma unroll
    for (int kk = 0; kk < 4; ++kk) {
        f16x8 ah[2], al[2], bh[2], bl[2];
        int chunk = kk * 4 + lg;
        #pragma unroll
        for (int m = 0; m < 2; ++m) {
            int row = wy * 32 + m * 16 + lr;
            int off = row * 128 + ((chunk ^ (row & 7)) * 8);
            ah[m] = *(f16x8*)&Ahi[off];
            al[m] = *(f16x8*)&Alo[off];
        }
        #pragma unroll
        for (int n = 0; n < 2; ++n) {
            int row = wx * 32 + n * 16 + lr;
            int off = row * 128 + ((chunk ^ (row & 7)) * 8);
            bh[n] = *(f16x8*)&Bhi[off];
            bl[n] = *(f16x8*)&Blo[off];
        }
        #pragma unroll
        for (int m = 0; m < 2; ++m)
            #pragma unroll
            for (int n = 0; n < 2; ++n) {
                acc1[m][n] = __builtin_amdgcn_mfma_f32_16x16x32_f16(ah[m], bh[n], acc1[m][n], 0, 0, 0);
                acc2[m][n] = __builtin_amdgcn_mfma_f32_16x16x32_f16(ah[m], bl[n], acc2[m][n], 0, 0, 0);
                acc2[m][n] = __builtin_amdgcn_mfma_f32_16x16x32_f16(al[m], bh[n], acc2[m][n], 0, 0, 0);
            }
    }

    // C-write (col=lane&15, row=(lane>>4)*4+reg) + fused hist (copy by t&1)
    uint32* hrow = hs[t & 1];
    #pragma unroll
    for (int m = 0; m < 2; ++m) {
        #pragma unroll
        for (int n = 0; n < 2; ++n) {
            #pragma unroll
            for (int r = 0; r < 4; ++r) {
                int gi = i0 + wy * 32 + m * 16 + lg * 4 + r;
                int gj = j0 + wx * 32 + n * 16 + lr;
                float v = acc1[m][n][r] + acc2[m][n][r] * LO_UNSCALE;
                if (gi == gj) v -= 1.0f;          // subtract eye
                S[(size_t)gi * NN + gj] = v;
                atomicAdd(&hrow[bin_of(v, LO1, INV1)], 1u);
            }
        }
    }
    __syncthreads();
    uint32* hcopy = &hist1[(uint32)(bid & (NCOPY1 - 1)) * NB];
    for (int i = t; i < NB; i += 256) {
        uint32 v = hs[0][i] + hs[1][i];
        if (v) atomicAdd(&hcopy[i], v);
    }
}

// fused scan1 + level-2 histogram + candidate gather + colsum-above-B1.
__global__ __launch_bounds__(256) void k_h2c(const float4* __restrict__ S4,
                                             const uint32* __restrict__ hist1,
                                             uint32* __restrict__ hist2,
                                             float* __restrict__ candV,
                                             uint32* __restrict__ candF,
                                             float* __restrict__ csumG,
                                             uint32* __restrict__ scal) {
    __shared__ uint32 hs[NB];        // 8 KB: first merged hist1, then level-2 hist
    __shared__ uint32 csum[256];     // 1 KB
    __shared__ float  cs2[4][256];   // 4 KB  per-rowgroup column sums
    __shared__ float  bvv[LBUF];     // 8 KB
    __shared__ uint32 bff[LBUF];     // 8 KB
    __shared__ uint32 bcnt, gbase, sB1;
    int t = threadIdx.x;
    int cw = blockIdx.x & 7;         // column window: 256 cols
    int rg = blockIdx.x >> 3;        // row group: 32 rows (64 groups)

    // ---- phase 0: merge hist1 shards, scan for B1/K2 (redundant per block) ----
    {
        uint32 s8[8];
        #pragma unroll
        for (int u = 0; u < 8; ++u) s8[u] = 0;
        #pragma unroll
        for (int cp = 0; cp < NCOPY1; ++cp) {
            const uint4* hp = (const uint4*)&hist1[cp * NB + t * 8];
            uint4 a = hp[0], b = hp[1];
            s8[0] += a.x; s8[1] += a.y; s8[2] += a.z; s8[3] += a.w;
            s8[4] += b.x; s8[5] += b.y; s8[6] += b.z; s8[7] += b.w;
        }
        uint32 tot = 0;
        #pragma unroll
        for (int u = 0; u < 8; ++u) { hs[t * 8 + u] = s8[u]; tot += s8[u]; }
        csum[t] = tot;
    }
    if (t == 0) bcnt = 0;
    __syncthreads();
    if (t == 0) {
        uint32 K = KEEPK, cum = 0;
        int cb = 255;
        for (; cb > 0; --cb) {
            if (cum + csum[cb] >= K) break;
            cum += csum[cb];
        }
        int b;
        for (b = cb * 8 + 7; b > cb * 8; --b) {
            if (cum + hs[b] >= K) break;
            cum += hs[b];
        }
        sB1 = (uint32)b;
        scal[0] = (uint32)b;      // B1 (same value from every block)
        scal[1] = K - cum;        // K2 (same value from every block)
    }
    __syncthreads();
    int B1 = (int)sB1;
    // re-zero hs for the level-2 histogram
    for (int i = t; i < NB; i += 256) hs[i] = 0;
    __syncthreads();

    float lo2 = LO1 + (float)B1 * BINW1;
    int rown = t >> 6;               // 0..3
    int c64 = t & 63;                // float4-group within window
    int colbase = cw * 256 + c64 * 4;
    float creg[4] = {0.f, 0.f, 0.f, 0.f};
    #pragma unroll
    for (int it = 0; it < 8; ++it) {
        int row = rg * 32 + it * 4 + rown;
        float4 v = S4[(size_t)row * (NN / 4) + cw * 64 + c64];
        #pragma unroll
        for (int e = 0; e < 4; ++e) {
            float xv = (&v.x)[e];
            int b1 = bin_of(xv, LO1, INV1);
            if (b1 > B1) {
                creg[e] += xv;
            } else if (b1 == B1) {
                atomicAdd(&hs[bin_of(xv, lo2, INV2)], 1u);
                uint32 p = atomicAdd(&bcnt, 1u);
                uint32 flat = (uint32)row * (uint32)NN + (uint32)(colbase + e);
                if (p < LBUF) { bvv[p] = xv; bff[p] = flat; }
                else {  // overflow safety (statistically unreachable)
                    uint32 g = atomicAdd(&scal[5], 1u);
                    if (g < CAND_CAP) { candV[g] = xv; candF[g] = flat; }
                }
            }
        }
    }
    #pragma unroll
    for (int e = 0; e < 4; ++e) cs2[rown][c64 * 4 + e] = creg[e];
    __syncthreads();
    {   // thread t owns window-column t; 4 shards
        float s = cs2[0][t] + cs2[1][t] + cs2[2][t] + cs2[3][t];
        uint32 shard = (uint32)(blockIdx.x & (CSHARDS - 1));
        if (s != 0.f) atomicAdd(&csumG[shard * NN + cw * 256 + t], s);
    }
    uint32 n = bcnt > LBUF ? LBUF : bcnt;
    if (t == 0) gbase = atomicAdd(&scal[5], n);
    __syncthreads();
    uint32 gb = gbase;
    for (uint32 i = t; i < n; i += 256u) {
        uint32 g = gb + i;
        if (g < CAND_CAP) { candV[g] = bvv[i]; candF[g] = bff[i]; }
    }
    for (int i = t; i < NB; i += 256) {
        uint32 v = hs[i];
        if (v) atomicAdd(&hist2[i], v);
    }
}

// fused scan2+filter: each block redundantly scans hist2 (8 KB, L2) -> B2/need,
// then filters B1-candidates to bin B2 (LDS-staged, one global atomic per block).
__global__ __launch_bounds__(256) void k_filt(const uint32* __restrict__ hist2,
                                              const float* __restrict__ candV,
                                              const uint32* __restrict__ candF,
                                              float* __restrict__ c2V,
                                              uint32* __restrict__ c2F,
                                              uint32* __restrict__ scal) {
    __shared__ uint32 sh[NB];        // 8 KB
    __shared__ uint32 csum[256];
    __shared__ float  fv[1024];
    __shared__ uint32 ff[1024];
    __shared__ uint32 fcnt, fbase, sB2;
    int t = threadIdx.x;
    if (t == 0) fcnt = 0;
    // inline level-2 scan (same in every block; deterministic)
    uint32 tot = 0;
    #pragma unroll
    for (int u = 0; u < 8; ++u) {
        uint32 s = hist2[t * 8 + u];
        sh[t * 8 + u] = s; tot += s;
    }
    csum[t] = tot;
    __syncthreads();
    if (t == 0) {
        uint32 K = scal[1], cum = 0;
        int cb = 255;
        for (; cb > 0; --cb) {
            if (cum + csum[cb] >= K) break;
            cum += csum[cb];
        }
        int b;
        for (b = cb * 8 + 7; b > cb * 8; --b) {
            if (cum + sh[b] >= K) break;
            cum += sh[b];
        }
        sB2 = (uint32)b;
        if (blockIdx.x == 0) {
            scal[2] = (uint32)b;     // B2 (for reference)
            scal[3] = K - cum;       // need within B2 (k_degpick reads this)
        }
    }
    __syncthreads();
    uint32 cnt = scal[5];
    if (cnt > CAND_CAP) cnt = CAND_CAP;
    int B1 = (int)scal[0], B2 = (int)sB2;
    float lo2 = LO1 + (float)B1 * BINW1;
    for (uint32 i = blockIdx.x * 256u + t; i < cnt; i += gridDim.x * 256u) {
        float v = candV[i];
        if (bin_of(v, lo2, INV2) == B2) {
            uint32 p = atomicAdd(&fcnt, 1u);
            if (p < 1024u) { fv[p] = v; ff[p] = candF[i]; }
            else {  // overflow safety
                uint32 g = atomicAdd(&scal[8], 1u);
                if (g < C2_CAP) { c2V[g] = v; c2F[g] = candF[i]; }
            }
        }
    }
    __syncthreads();
    uint32 n = fcnt > 1024u ? 1024u : fcnt;
    if (t == 0) fbase = atomicAdd(&scal[8], n);
    __syncthreads();
    uint32 fb = fbase;
    for (uint32 i = t; i < n; i += 256u) {
        uint32 g = fb + i;
        if (g < C2_CAP) { c2V[g] = fv[i]; c2F[g] = ff[i]; }
    }
}

// fused pick + degsum: every block redundantly computes exact tau/cutoff from
// the tiny B2-filtered list (deterministic), block 0 persists to scal; then
// deg[j] = merged colsum shards, degc[j] += selected B1-bin candidates.
__global__ __launch_bounds__(256) void k_degpick(const float* __restrict__ csumG,
                                                 const float* __restrict__ candV,
                                                 const uint32* __restrict__ candF,
                                                 const float* __restrict__ c2V,
                                                 const uint32* __restrict__ c2F,
                                                 uint32* __restrict__ scal,
                                                 float* __restrict__ deg,
                                                 float* __restrict__ degc) {
    __shared__ float  sv[C2_CAP];
    __shared__ uint32 sf[C2_CAP];
    __shared__ float  s_tau;
    __shared__ uint32 s_cut;
    int t = threadIdx.x;
    int tid = blockIdx.x * 256 + t;   // 64 blocks x 256 = 16384
    uint32 c2 = scal[8];
    if (c2 > C2_CAP) c2 = C2_CAP;
    for (uint32 i = t; i < c2; i += 256u) { sv[i] = c2V[i]; sf[i] = c2F[i]; }
    // deg merge (independent of tau)
    if (tid < NN) {
        float s = 0.f;
        #pragma unroll
        for (int cp = 0; cp < CSHARDS; ++cp) s += csumG[cp * NN + tid];
        deg[tid] = s;
    }
    __syncthreads();
    if (t == 0) {
        uint32 need = scal[3];
        if (need > c2) need = c2;
        if (c2 == 0) {
            s_tau = 3.0e38f; s_cut = 0u;
        } else {
            if (need == 0) need = 1;
            for (uint32 s = 0; s < need; ++s) {
                uint32 best = s;
                for (uint32 q = s + 1; q < c2; ++q) {
                    if (sv[q] > sv[best] || (sv[q] == sv[best] && sf[q] < sf[best])) best = q;
                }
                float tv = sv[s]; sv[s] = sv[best]; sv[best] = tv;
                uint32 tf = sf[s]; sf[s] = sf[best]; sf[best] = tf;
            }
            s_tau = sv[need - 1];
            s_cut = sf[need - 1];
        }
        if (blockIdx.x == 0) {
            scal[6] = __float_as_uint(s_tau);   // tau (for k_agg)
            scal[7] = s_cut;                    // cutoff
        }
    }
    __syncthreads();
    float tau = s_tau;
    uint32 cutoff = s_cut;
    uint32 cnt = scal[5];
    if (cnt > CAND_CAP) cnt = CAND_CAP;
    for (uint32 i = (uint32)tid; i < cnt; i += 16384u) {
        float v = candV[i];
        uint32 flat = candF[i];
        if (v > tau || (v == tau && flat <= cutoff))
            atomicAdd(&degc[flat & (NN - 1)], v);
    }
}

// part[p][j][f] = sum_{i in chunk p} sel(i,j)*S[i][j]*dinv[i]*h[i][f] via bf16 MFMA.
// NPART=16 -> 512 blocks -> 2 blocks/CU (staging of one overlaps MFMA of other).
__global__ __launch_bounds__(256) void k_agg(const float* __restrict__ S,
                                             const float* __restrict__ h,
                                             const float* __restrict__ deg,
                                             const float* __restrict__ degc,
                                             const uint32* __restrict__ scal,
                                             _Float16* __restrict__ part) {
    __shared__ unsigned short Aw[64 * 64];    // 8 KB, [j][i] swizzled
    __shared__ unsigned short Bh[128 * 64];   // 16 KB, [f][i] swizzled
    int t = threadIdx.x;
    int j0 = blockIdx.x * 64;
    int p = blockIdx.y;
    int ibase = p * (NN / NPART);   // 128 rows per part
    float tau = __uint_as_float(scal[6]);
    uint32 cutoff = scal[7];
    int wid = t >> 6, l = t & 63;
    int wy = wid >> 1, wx = wid & 1;
    int lr = l & 15, lg = l >> 4;

    f32x4 acc[2][4];
    #pragma unroll
    for (int m = 0; m < 2; ++m)
        #pragma unroll
        for (int n = 0; n < 4; ++n) acc[m][n] = (f32x4){0.f, 0.f, 0.f, 0.f};

    #pragma unroll
    for (int cc = 0; cc < (NN / NPART) / 64; ++cc) {   // 2 iterations
        int ib = ibase + cc * 64;
        __syncthreads();
        // stage A: masked S row-reads -> bf16
        #pragma unroll
        for (int u = 0; u < 2; ++u) {
            int id = u * 256 + t;
            int r = id >> 3, c = id & 7;
            int gj = j0 + r;
            unsigned short w8[8];
            #pragma unroll
            for (int q = 0; q < 2; ++q) {
                float4 v = *(const float4*)&S[(size_t)gj * NN + ib + c * 8 + q * 4];
                #pragma unroll
                for (int e = 0; e < 4; ++e) {
                    int gi = ib + c * 8 + q * 4 + e;
                    float vv = (&v.x)[e];
                    uint32 flat = (uint32)gi * (uint32)NN + (uint32)gj;
                    bool sel = (vv > tau) || (vv == tau && flat <= cutoff);
                    w8[q * 4 + e] = f2bf(sel ? vv : 0.f);
                }
            }
            *(uint4*)&Aw[r * 64 + ((c ^ (r & 7)) * 8)] = pack8(w8);
        }
        // stage B: transpose dinv-scaled h -> [f][i] bf16, swizzled
        {
            int i = t & 63, fh = (t >> 6) * 32;
            int gi = ib + i;
            float di = rsqrtf(deg[gi] + degc[gi] + 1.0f);
            #pragma unroll
            for (int q = 0; q < 8; ++q) {
                int f = fh + q * 4;
                float4 hv = *(const float4*)&h[(size_t)gi * FF + f];
                #pragma unroll
                for (int e = 0; e < 4; ++e) {
                    int fr = f + e;
                    Bh[fr * 64 + (((i >> 3) ^ (fr & 7)) * 8 + (i & 7))] =
                        f2bf((&hv.x)[e] * di);
                }
            }
        }
        __syncthreads();
        #pragma unroll
        for (int kk = 0; kk < 2; ++kk) {
            bf16x8 a[2], b[4];
            int chunk = kk * 4 + lg;
            #pragma unroll
            for (int m = 0; m < 2; ++m) {
                int row = wy * 32 + m * 16 + lr;
                a[m] = *(bf16x8*)&Aw[row * 64 + ((chunk ^ (row & 7)) * 8)];
            }
            #pragma unroll
            for (int n = 0; n < 4; ++n) {
                int row = wx * 64 + n * 16 + lr;
                b[n] = *(bf16x8*)&Bh[row * 64 + ((chunk ^ (row & 7)) * 8)];
            }
            #pragma unroll
            for (int m = 0; m < 2; ++m)
                #pragma unroll
                for (int n = 0; n < 4; ++n)
                    acc[m][n] = __builtin_amdgcn_mfma_f32_16x16x32_bf16(a[m], b[n], acc[m][n], 0, 0, 0);
        }
    }
    #pragma unroll
    for (int m = 0; m < 2; ++m)
        #pragma unroll
        for (int n = 0; n < 4; ++n)
            #pragma unroll
            for (int r = 0; r < 4; ++r) {
                int gj = j0 + wy * 32 + m * 16 + lg * 4 + r;
                int gf = wx * 64 + n * 16 + lr;
                part[((size_t)p * NN + gj) * FF + gf] = (_Float16)acc[m][n][r];
            }
}

// out[j][f] = b[f] + dj*(dj*h[j][f] + sum_p part[p][j][f]), dj = rsqrt(deg+degc+1)
__global__ __launch_bounds__(256) void k_reduce(const _Float16* __restrict__ part,
                                                const float* __restrict__ h,
                                                const float* __restrict__ deg,
                                                const float* __restrict__ degc,
                                                const float* __restrict__ bvec,
                                                float* __restrict__ out) {
    int idx4 = blockIdx.x * 256 + threadIdx.x;   // 65536 groups of 4 f-elems
    int j = idx4 >> 5;
    int f4 = (idx4 & 31) * 4;
    size_t offh = (size_t)j * FF + f4;           // element offset
    const f16x4* p4 = (const f16x4*)part;
    float4 s = {0.f, 0.f, 0.f, 0.f};
    #pragma unroll
    for (int p = 0; p < NPART; ++p) {
        f16x4 v = p4[((size_t)p * NN * FF + offh) >> 2];
        s.x += (float)v[0]; s.y += (float)v[1];
        s.z += (float)v[2]; s.w += (float)v[3];
    }
    float dj = rsqrtf(deg[j] + degc[j] + 1.0f);
    float4 hv = *(const float4*)&h[offh];
    float4 bv = *(const float4*)&bvec[f4];
    float4 o;
    o.x = bv.x + dj * (dj * hv.x + s.x);
    o.y = bv.y + dj * (dj * hv.y + s.y);
    o.z = bv.z + dj * (dj * hv.z + s.z);
    o.w = bv.w + dj * (dj * hv.w + s.w);
    *(float4*)&out[offh] = o;
}

extern "C" void kernel_launch(void* const* d_in, const int* in_sizes, int n_in,
                              void* d_out, int out_size, void* d_ws, size_t ws_size,
                              hipStream_t stream) {
    const float* x = (const float*)d_in[0];   // [1,2048,128]
    const float* W = (const float*)d_in[1];   // [128,128]
    const float* b = (const float*)d_in[2];   // [128]
    float* out = (float*)d_out;

    if (ws_size < WS_NEEDED) return;  // insufficient scratch: fail visibly

    char* ws = (char*)d_ws;
    float*          deg   = (float*)(ws + OFF_DEG);
    float*          degc  = (float*)(ws + OFF_DEGC);
    uint32*         scal  = (uint32*)(ws + OFF_SCAL);
    uint32*         hist1 = (uint32*)(ws + OFF_HIST1);
    uint32*         hist2 = (uint32*)(ws + OFF_HIST2);
    float*          csumG = (float*)(ws + OFF_CSUM);
    float*          candV = (float*)(ws + OFF_CANDV);
    uint32*         candF = (uint32*)(ws + OFF_CANDF);
    float*          c2V   = (float*)(ws + OFF_C2V);
    uint32*         c2F   = (uint32*)(ws + OFF_C2F);
    unsigned short* xhi   = (unsigned short*)(ws + OFF_XHI);
    unsigned short* xlo   = (unsigned short*)(ws + OFF_XLO);
    float*          h     = (float*)(ws + OFF_H);
    float*          S     = (float*)(ws + OFF_S);
    _Float16*       part  = (_Float16*)(ws + OFF_PART);

    k_prep<<<128, 256, 0, stream>>>(x, xhi, xlo, (float4*)ws);
    k_main<<<1152, 256, 0, stream>>>(x, W, xhi, xlo, S, hist1, h);
    k_h2c<<<512, 256, 0, stream>>>((const float4*)S, hist1, hist2, candV, candF, csumG, scal);
    k_filt<<<64, 256, 0, stream>>>(hist2, candV, candF, c2V, c2F, scal);
    k_degpick<<<64, 256, 0, stream>>>(csumG, candV, candF, c2V, c2F, scal, deg, degc);
    k_agg<<<dim3(32, NPART), 256, 0, stream>>>(S, h, deg, degc, scal, part);
    k_reduce<<<256, 256, 0, stream>>>(part, h, deg, degc, b, out);
}

// Round 17
// 89.592 us; speedup vs baseline: 1.1928x; 1.0167x over previous
//
#include <hip/hip_runtime.h>

typedef unsigned int uint32;
typedef __attribute__((ext_vector_type(8))) _Float16 f16x8;
typedef __attribute__((ext_vector_type(4))) _Float16 f16x4;
typedef __attribute__((ext_vector_type(8))) short bf16x8;
typedef __attribute__((ext_vector_type(4))) float f32x4;

#define NN 2048
#define FF 128
#define KEEPK 1258291u      // int(0.3 * 2048 * 2048)
#define NB 2048             // histogram bins per level
#define NCOPY1 16           // hist1 shards
#define CSHARDS 4           // colsum shards
#define LO1 (-4.0f)
#define BINW1 0.0625f       // 2^-4, exact
#define INV1 16.0f
#define INV2 32768.0f       // 2048 / BINW1 = 2^15, exact
#define CAND_CAP 131072u    // B1-bin population ~37k expected; 3.6x margin
#define LBUF 2048u          // per-block LDS candidate staging (k_h2c)
#define C2_CAP 4096u        // B2-filtered candidate capacity
#define NPART 16            // i-chunks for atomic-free aggregation (2 blocks/CU)
#define LO_SCALE 2048.0f    // 2^11: keep fp16 lo-part in normal range
#define LO_UNSCALE 4.8828125e-4f  // 2^-11

// workspace layout (bytes)  [ws_size = 256 MiB]
#define OFF_DEG    (0u)                 // float[2048]
#define OFF_DEGC   (8u*1024u)           // float[2048]
#define OFF_SCAL   (16u*1024u)          // uint[64]: 0=B1 1=K2 2=B2 3=need 5=c1 6=tau 7=cutoff 8=c2
#define OFF_HIST1  (17u*1024u)          // uint[16][2048] = 128K
#define OFF_HIST2  (145u*1024u)         // uint[2048] = 8K (unsharded)
#define OFF_CSUM   (153u*1024u)         // float[4][2048] = 32K
#define ZERO_BYTES (185u*1024u)         // region zeroed by k_prep
#define ZERO_F4    (11840u)             // ZERO_BYTES / 16
#define OFF_CANDV  (185u*1024u)         // float[131072] = 512K
#define OFF_CANDF  (697u*1024u)         // uint[131072]  = 512K
#define OFF_C2V    (1209u*1024u)        // float[4096] = 16K
#define OFF_C2F    (1225u*1024u)        // uint[4096]  = 16K
#define OFF_XHI    (1241u*1024u)        // fp16 hi(x) = 512K
#define OFF_XLO    (1753u*1024u)        // fp16 lo(x)*2048 = 512K
#define OFF_H      (2265u*1024u)        // float h = 1 MB
#define OFF_S      (3289u*1024u)        // float[2048*2048] = 16 MB
#define OFF_PART   (OFF_S + (uint32)NN*NN*4u)   // fp16[NPART][2048][128] = 8 MB
#define WS_NEEDED  ((size_t)OFF_PART + (size_t)NPART*NN*FF*2u)

__device__ __forceinline__ int bin_of(float v, float lo, float inv) {
    int b = (int)floorf((v - lo) * inv);
    return b < 0 ? 0 : (b > NB - 1 ? NB - 1 : b);
}

__device__ __forceinline__ unsigned short f2bf(float f) {   // round-to-nearest-even
    uint32 u = __float_as_uint(f);
    u += 0x7fffu + ((u >> 16) & 1u);
    return (unsigned short)(u >> 16);
}

__device__ __forceinline__ void split16(float v, unsigned short& hi, unsigned short& lo) {
    union { _Float16 f; unsigned short u; } a, b;
    a.f = (_Float16)v;
    float back = (float)a.f;
    b.f = (_Float16)((v - back) * LO_SCALE);
    hi = a.u; lo = b.u;
}

__device__ __forceinline__ uint4 pack8(const unsigned short* w) {  // 8 u16 -> uint4
    uint4 p;
    p.x = (uint32)w[0] | ((uint32)w[1] << 16);
    p.y = (uint32)w[2] | ((uint32)w[3] << 16);
    p.z = (uint32)w[4] | ((uint32)w[5] << 16);
    p.w = (uint32)w[6] | ((uint32)w[7] << 16);
    return p;
}

// one-shot split of x into fp16 hi/lo + fused zeroing of the accumulator region
__global__ __launch_bounds__(256) void k_prep(const float* __restrict__ x,
                                              unsigned short* __restrict__ xhi,
                                              unsigned short* __restrict__ xlo,
                                              float4* __restrict__ zbase) {
    int id = blockIdx.x * 256 + threadIdx.x;   // 32768 threads x 8 elems
    if ((uint32)id < ZERO_F4) zbase[id] = (float4){0.f, 0.f, 0.f, 0.f};
    float4 a0 = *(const float4*)&x[(size_t)id * 8];
    float4 a1 = *(const float4*)&x[(size_t)id * 8 + 4];
    unsigned short h8[8], l8[8];
    #pragma unroll
    for (int e = 0; e < 4; ++e) {
        split16((&a0.x)[e], h8[e], l8[e]);
        split16((&a1.x)[e], h8[4 + e], l8[4 + e]);
    }
    *(uint4*)&xhi[(size_t)id * 8] = pack8(h8);
    *(uint4*)&xlo[(size_t)id * 8] = pack8(l8);
}

// blocks [0,256): 128x128 tile of S = X*X^T - I (split-fp16 MFMA, fp32-accurate)
// + sharded hist1 (2 LDS copies). 4 waves (2x2), each 64x64 (4x4 16x16 frags).
// LDS: 4 x 32 KB staging + 16 KB hist = 144 KB -> 1 block/CU, 8 waves resident.
// blocks [256,384): h = X*W (fp32, 16 rows per block).
__global__ __launch_bounds__(256) void k_main(const float* __restrict__ x,
                                              const float* __restrict__ W,
                                              const unsigned short* __restrict__ xhi,
                                              const unsigned short* __restrict__ xlo,
                                              float* __restrict__ S,
                                              uint32* __restrict__ hist1,
                                              float* __restrict__ h) {
    __shared__ unsigned short Ahi[128 * 128];  // 32 KB each
    __shared__ unsigned short Alo[128 * 128];
    __shared__ unsigned short Bhi[128 * 128];
    __shared__ unsigned short Blo[128 * 128];
    __shared__ uint32 hs[2][NB];               // 16 KB (2 copies)
    int bid = blockIdx.x;
    int t = threadIdx.x;

    if (bid >= 256) {   // ---- h = X*W path ----
        int r0 = (bid - 256) * 16;
        int row = t >> 4, fg = t & 15;
        float acc[8];
        #pragma unroll
        for (int e = 0; e < 8; ++e) acc[e] = 0.f;
        for (int k = 0; k < FF; ++k) {
            float xr = x[(size_t)(r0 + row) * FF + k];
            float4 w0 = *(const float4*)&W[k * FF + fg * 8];
            float4 w1 = *(const float4*)&W[k * FF + fg * 8 + 4];
            acc[0] += xr * w0.x; acc[1] += xr * w0.y;
            acc[2] += xr * w0.z; acc[3] += xr * w0.w;
            acc[4] += xr * w1.x; acc[5] += xr * w1.y;
            acc[6] += xr * w1.z; acc[7] += xr * w1.w;
        }
        float4 o0 = {acc[0], acc[1], acc[2], acc[3]};
        float4 o1 = {acc[4], acc[5], acc[6], acc[7]};
        *(float4*)&h[(size_t)(r0 + row) * FF + fg * 8] = o0;
        *(float4*)&h[(size_t)(r0 + row) * FF + fg * 8 + 4] = o1;
        return;
    }

    // ---- sim path: 128x128 tile ----
    for (int i = t; i < NB; i += 256) { hs[0][i] = 0; hs[1][i] = 0; }
    int i0 = (bid >> 4) * 128, j0 = (bid & 15) * 128;
    #pragma unroll
    for (int u = 0; u < 8; ++u) {
        int id = u * 256 + t;           // 2048 chunks per array (128 rows x 16)
        int r = id >> 4, c = id & 15;
        int sl = (c ^ (r & 7)) * 8;     // swizzled elem offset
        *(uint4*)&Ahi[r * 128 + sl] = *(const uint4*)&xhi[(size_t)(i0 + r) * FF + c * 8];
        *(uint4*)&Alo[r * 128 + sl] = *(const uint4*)&xlo[(size_t)(i0 + r) * FF + c * 8];
        *(uint4*)&Bhi[r * 128 + sl] = *(const uint4*)&xhi[(size_t)(j0 + r) * FF + c * 8];
        *(uint4*)&Blo[r * 128 + sl] = *(const uint4*)&xlo[(size_t)(j0 + r) * FF + c * 8];
    }
    __syncthreads();

    int wid = t >> 6, l = t & 63;
    int wy = wid >> 1, wx = wid & 1;
    int lr = l & 15, lg = l >> 4;
    f32x4 acc1[4][4], acc2[4][4];
    #pragma unroll
    for (int m = 0; m < 4; ++m)
        #pragma unroll
        for (int n = 0; n < 4; ++n) {
            acc1[m][n] = (f32x4){0.f, 0.f, 0.f, 0.f};
            acc2[m][n] = (f32x4){0.f, 0.f, 0.f, 0.f};
        }

    #pragma unroll
    for (int kk = 0; kk < 4; ++kk) {
        f16x8 ah[4], al[4], bh[4], bl[4];
        int chunk = kk * 4 + lg;
        #pragma unroll
        for (int m = 0; m < 4; ++m) {
            int row = wy * 64 + m * 16 + lr;
            int off = row * 128 + ((chunk ^ (row & 7)) * 8);
            ah[m] = *(f16x8*)&Ahi[off];
            al[m] = *(f16x8*)&Alo[off];
        }
        #pragma unroll
        for (int n = 0; n < 4; ++n) {
            int row = wx * 64 + n * 16 + lr;
            int off = row * 128 + ((chunk ^ (row & 7)) * 8);
            bh[n] = *(f16x8*)&Bhi[off];
            bl[n] = *(f16x8*)&Blo[off];
        }
        #pragma unroll
        for (int m = 0; m < 4; ++m)
            #pragma unroll
            for (int n = 0; n < 4; ++n) {
                acc1[m][n] = __builtin_amdgcn_mfma_f32_16x16x32_f16(ah[m], bh[n], acc1[m][n], 0, 0, 0);
                acc2[m][n] = __builtin_amdgcn_mfma_f32_16x16x32_f16(ah[m], bl[n], acc2[m][n], 0, 0, 0);
                acc2[m][n] = __builtin_amdgcn_mfma_f32_16x16x32_f16(al[m], bh[n], acc2[m][n], 0, 0, 0);
            }
    }

    // C-write (col=lane&15, row=(lane>>4)*4+reg) + fused hist (copy by t&1)
    uint32* hrow = hs[t & 1];
    #pragma unroll
    for (int m = 0; m < 4; ++m) {
        #pragma unroll
        for (int n = 0; n < 4; ++n) {
            #pragma unroll
            for (int r = 0; r < 4; ++r) {
                int gi = i0 + wy * 64 + m * 16 + lg * 4 + r;
                int gj = j0 + wx * 64 + n * 16 + lr;
                float v = acc1[m][n][r] + acc2[m][n][r] * LO_UNSCALE;
                if (gi == gj) v -= 1.0f;          // subtract eye
                S[(size_t)gi * NN + gj] = v;
                atomicAdd(&hrow[bin_of(v, LO1, INV1)], 1u);
            }
        }
    }
    __syncthreads();
    uint32* hcopy = &hist1[(uint32)(bid & (NCOPY1 - 1)) * NB];
    for (int i = t; i < NB; i += 256) {
        uint32 v = hs[0][i] + hs[1][i];
        if (v) atomicAdd(&hcopy[i], v);
    }
}

// fused scan1 + level-2 histogram + candidate gather + colsum-above-B1.
__global__ __launch_bounds__(256) void k_h2c(const float4* __restrict__ S4,
                                             const uint32* __restrict__ hist1,
                                             uint32* __restrict__ hist2,
                                             float* __restrict__ candV,
                                             uint32* __restrict__ candF,
                                             float* __restrict__ csumG,
                                             uint32* __restrict__ scal) {
    __shared__ uint32 hs[NB];        // 8 KB: first merged hist1, then level-2 hist
    __shared__ uint32 csum[256];     // 1 KB
    __shared__ float  cs2[4][256];   // 4 KB  per-rowgroup column sums
    __shared__ float  bvv[LBUF];     // 8 KB
    __shared__ uint32 bff[LBUF];     // 8 KB
    __shared__ uint32 bcnt, gbase, sB1;
    int t = threadIdx.x;
    int cw = blockIdx.x & 7;         // column window: 256 cols
    int rg = blockIdx.x >> 3;        // row group: 32 rows (64 groups)

    // ---- phase 0: merge hist1 shards, scan for B1/K2 (redundant per block) ----
    {
        uint32 s8[8];
        #pragma unroll
        for (int u = 0; u < 8; ++u) s8[u] = 0;
        #pragma unroll
        for (int cp = 0; cp < NCOPY1; ++cp) {
            const uint4* hp = (const uint4*)&hist1[cp * NB + t * 8];
            uint4 a = hp[0], b = hp[1];
            s8[0] += a.x; s8[1] += a.y; s8[2] += a.z; s8[3] += a.w;
            s8[4] += b.x; s8[5] += b.y; s8[6] += b.z; s8[7] += b.w;
        }
        uint32 tot = 0;
        #pragma unroll
        for (int u = 0; u < 8; ++u) { hs[t * 8 + u] = s8[u]; tot += s8[u]; }
        csum[t] = tot;
    }
    if (t == 0) bcnt = 0;
    __syncthreads();
    if (t == 0) {
        uint32 K = KEEPK, cum = 0;
        int cb = 255;
        for (; cb > 0; --cb) {
            if (cum + csum[cb] >= K) break;
            cum += csum[cb];
        }
        int b;
        for (b = cb * 8 + 7; b > cb * 8; --b) {
            if (cum + hs[b] >= K) break;
            cum += hs[b];
        }
        sB1 = (uint32)b;
        scal[0] = (uint32)b;      // B1 (same value from every block)
        scal[1] = K - cum;        // K2 (same value from every block)
    }
    __syncthreads();
    int B1 = (int)sB1;
    // re-zero hs for the level-2 histogram
    for (int i = t; i < NB; i += 256) hs[i] = 0;
    __syncthreads();

    float lo2 = LO1 + (float)B1 * BINW1;
    int rown = t >> 6;               // 0..3
    int c64 = t & 63;                // float4-group within window
    int colbase = cw * 256 + c64 * 4;
    float creg[4] = {0.f, 0.f, 0.f, 0.f};
    #pragma unroll
    for (int it = 0; it < 8; ++it) {
        int row = rg * 32 + it * 4 + rown;
        float4 v = S4[(size_t)row * (NN / 4) + cw * 64 + c64];
        #pragma unroll
        for (int e = 0; e < 4; ++e) {
            float xv = (&v.x)[e];
            int b1 = bin_of(xv, LO1, INV1);
            if (b1 > B1) {
                creg[e] += xv;
            } else if (b1 == B1) {
                atomicAdd(&hs[bin_of(xv, lo2, INV2)], 1u);
                uint32 p = atomicAdd(&bcnt, 1u);
                uint32 flat = (uint32)row * (uint32)NN + (uint32)(colbase + e);
                if (p < LBUF) { bvv[p] = xv; bff[p] = flat; }
                else {  // overflow safety (statistically unreachable)
                    uint32 g = atomicAdd(&scal[5], 1u);
                    if (g < CAND_CAP) { candV[g] = xv; candF[g] = flat; }
                }
            }
        }
    }
    #pragma unroll
    for (int e = 0; e < 4; ++e) cs2[rown][c64 * 4 + e] = creg[e];
    __syncthreads();
    {   // thread t owns window-column t; 4 shards
        float s = cs2[0][t] + cs2[1][t] + cs2[2][t] + cs2[3][t];
        uint32 shard = (uint32)(blockIdx.x & (CSHARDS - 1));
        if (s != 0.f) atomicAdd(&csumG[shard * NN + cw * 256 + t], s);
    }
    uint32 n = bcnt > LBUF ? LBUF : bcnt;
    if (t == 0) gbase = atomicAdd(&scal[5], n);
    __syncthreads();
    uint32 gb = gbase;
    for (uint32 i = t; i < n; i += 256u) {
        uint32 g = gb + i;
        if (g < CAND_CAP) { candV[g] = bvv[i]; candF[g] = bff[i]; }
    }
    for (int i = t; i < NB; i += 256) {
        uint32 v = hs[i];
        if (v) atomicAdd(&hist2[i], v);
    }
}

// fused scan2+filter: each block redundantly scans hist2 (8 KB, L2) -> B2/need,
// then filters B1-candidates to bin B2 (LDS-staged, one global atomic per block).
__global__ __launch_bounds__(256) void k_filt(const uint32* __restrict__ hist2,
                                              const float* __restrict__ candV,
                                              const uint32* __restrict__ candF,
                                              float* __restrict__ c2V,
                                              uint32* __restrict__ c2F,
                                              uint32* __restrict__ scal) {
    __shared__ uint32 sh[NB];        // 8 KB
    __shared__ uint32 csum[256];
    __shared__ float  fv[1024];
    __shared__ uint32 ff[1024];
    __shared__ uint32 fcnt, fbase, sB2;
    int t = threadIdx.x;
    if (t == 0) fcnt = 0;
    // inline level-2 scan (same in every block; deterministic)
    uint32 tot = 0;
    #pragma unroll
    for (int u = 0; u < 8; ++u) {
        uint32 s = hist2[t * 8 + u];
        sh[t * 8 + u] = s; tot += s;
    }
    csum[t] = tot;
    __syncthreads();
    if (t == 0) {
        uint32 K = scal[1], cum = 0;
        int cb = 255;
        for (; cb > 0; --cb) {
            if (cum + csum[cb] >= K) break;
            cum += csum[cb];
        }
        int b;
        for (b = cb * 8 + 7; b > cb * 8; --b) {
            if (cum + sh[b] >= K) break;
            cum += sh[b];
        }
        sB2 = (uint32)b;
        if (blockIdx.x == 0) {
            scal[2] = (uint32)b;     // B2 (for reference)
            scal[3] = K - cum;       // need within B2 (k_degpick reads this)
        }
    }
    __syncthreads();
    uint32 cnt = scal[5];
    if (cnt > CAND_CAP) cnt = CAND_CAP;
    int B1 = (int)scal[0], B2 = (int)sB2;
    float lo2 = LO1 + (float)B1 * BINW1;
    for (uint32 i = blockIdx.x * 256u + t; i < cnt; i += gridDim.x * 256u) {
        float v = candV[i];
        if (bin_of(v, lo2, INV2) == B2) {
            uint32 p = atomicAdd(&fcnt, 1u);
            if (p < 1024u) { fv[p] = v; ff[p] = candF[i]; }
            else {  // overflow safety
                uint32 g = atomicAdd(&scal[8], 1u);
                if (g < C2_CAP) { c2V[g] = v; c2F[g] = candF[i]; }
            }
        }
    }
    __syncthreads();
    uint32 n = fcnt > 1024u ? 1024u : fcnt;
    if (t == 0) fbase = atomicAdd(&scal[8], n);
    __syncthreads();
    uint32 fb = fbase;
    for (uint32 i = t; i < n; i += 256u) {
        uint32 g = fb + i;
        if (g < C2_CAP) { c2V[g] = fv[i]; c2F[g] = ff[i]; }
    }
}

// fused pick + degsum: every block redundantly computes exact tau/cutoff from
// the tiny B2-filtered list (deterministic), block 0 persists to scal; then
// deg[j] = merged colsum shards, degc[j] += selected B1-bin candidates.
__global__ __launch_bounds__(256) void k_degpick(const float* __restrict__ csumG,
                                                 const float* __restrict__ candV,
                                                 const uint32* __restrict__ candF,
                                                 const float* __restrict__ c2V,
                                                 const uint32* __restrict__ c2F,
                                                 uint32* __restrict__ scal,
                                                 float* __restrict__ deg,
                                                 float* __restrict__ degc) {
    __shared__ float  sv[C2_CAP];
    __shared__ uint32 sf[C2_CAP];
    __shared__ float  s_tau;
    __shared__ uint32 s_cut;
    int t = threadIdx.x;
    int tid = blockIdx.x * 256 + t;   // 64 blocks x 256 = 16384
    uint32 c2 = scal[8];
    if (c2 > C2_CAP) c2 = C2_CAP;
    for (uint32 i = t; i < c2; i += 256u) { sv[i] = c2V[i]; sf[i] = c2F[i]; }
    // deg merge (independent of tau)
    if (tid < NN) {
        float s = 0.f;
        #pragma unroll
        for (int cp = 0; cp < CSHARDS; ++cp) s += csumG[cp * NN + tid];
        deg[tid] = s;
    }
    __syncthreads();
    if (t == 0) {
        uint32 need = scal[3];
        if (need > c2) need = c2;
        if (c2 == 0) {
            s_tau = 3.0e38f; s_cut = 0u;
        } else {
            if (need == 0) need = 1;
            for (uint32 s = 0; s < need; ++s) {
                uint32 best = s;
                for (uint32 q = s + 1; q < c2; ++q) {
                    if (sv[q] > sv[best] || (sv[q] == sv[best] && sf[q] < sf[best])) best = q;
                }
                float tv = sv[s]; sv[s] = sv[best]; sv[best] = tv;
                uint32 tf = sf[s]; sf[s] = sf[best]; sf[best] = tf;
            }
            s_tau = sv[need - 1];
            s_cut = sf[need - 1];
        }
        if (blockIdx.x == 0) {
            scal[6] = __float_as_uint(s_tau);   // tau (for k_agg)
            scal[7] = s_cut;                    // cutoff
        }
    }
    __syncthreads();
    float tau = s_tau;
    uint32 cutoff = s_cut;
    uint32 cnt = scal[5];
    if (cnt > CAND_CAP) cnt = CAND_CAP;
    for (uint32 i = (uint32)tid; i < cnt; i += 16384u) {
        float v = candV[i];
        uint32 flat = candF[i];
        if (v > tau || (v == tau && flat <= cutoff))
            atomicAdd(&degc[flat & (NN - 1)], v);
    }
}

// part[p][j][f] = sum_{i in chunk p} sel(i,j)*S[i][j]*dinv[i]*h[i][f] via bf16 MFMA.
// NPART=16 -> 512 blocks -> 2 blocks/CU (staging of one overlaps MFMA of other).
__global__ __launch_bounds__(256) void k_agg(const float* __restrict__ S,
                                             const float* __restrict__ h,
                                             const float* __restrict__ deg,
                                             const float* __restrict__ degc,
                                             const uint32* __restrict__ scal,
                                             _Float16* __restrict__ part) {
    __shared__ unsigned short Aw[64 * 64];    // 8 KB, [j][i] swizzled
    __shared__ unsigned short Bh[128 * 64];   // 16 KB, [f][i] swizzled
    int t = threadIdx.x;
    int j0 = blockIdx.x * 64;
    int p = blockIdx.y;
    int ibase = p * (NN / NPART);   // 128 rows per part
    float tau = __uint_as_float(scal[6]);
    uint32 cutoff = scal[7];
    int wid = t >> 6, l = t & 63;
    int wy = wid >> 1, wx = wid & 1;
    int lr = l & 15, lg = l >> 4;

    f32x4 acc[2][4];
    #pragma unroll
    for (int m = 0; m < 2; ++m)
        #pragma unroll
        for (int n = 0; n < 4; ++n) acc[m][n] = (f32x4){0.f, 0.f, 0.f, 0.f};

    #pragma unroll
    for (int cc = 0; cc < (NN / NPART) / 64; ++cc) {   // 2 iterations
        int ib = ibase + cc * 64;
        __syncthreads();
        // stage A: masked S row-reads -> bf16
        #pragma unroll
        for (int u = 0; u < 2; ++u) {
            int id = u * 256 + t;
            int r = id >> 3, c = id & 7;
            int gj = j0 + r;
            unsigned short w8[8];
            #pragma unroll
            for (int q = 0; q < 2; ++q) {
                float4 v = *(const float4*)&S[(size_t)gj * NN + ib + c * 8 + q * 4];
                #pragma unroll
                for (int e = 0; e < 4; ++e) {
                    int gi = ib + c * 8 + q * 4 + e;
                    float vv = (&v.x)[e];
                    uint32 flat = (uint32)gi * (uint32)NN + (uint32)gj;
                    bool sel = (vv > tau) || (vv == tau && flat <= cutoff);
                    w8[q * 4 + e] = f2bf(sel ? vv : 0.f);
                }
            }
            *(uint4*)&Aw[r * 64 + ((c ^ (r & 7)) * 8)] = pack8(w8);
        }
        // stage B: transpose dinv-scaled h -> [f][i] bf16, swizzled
        {
            int i = t & 63, fh = (t >> 6) * 32;
            int gi = ib + i;
            float di = rsqrtf(deg[gi] + degc[gi] + 1.0f);
            #pragma unroll
            for (int q = 0; q < 8; ++q) {
                int f = fh + q * 4;
                float4 hv = *(const float4*)&h[(size_t)gi * FF + f];
                #pragma unroll
                for (int e = 0; e < 4; ++e) {
                    int fr = f + e;
                    Bh[fr * 64 + (((i >> 3) ^ (fr & 7)) * 8 + (i & 7))] =
                        f2bf((&hv.x)[e] * di);
                }
            }
        }
        __syncthreads();
        #pragma unroll
        for (int kk = 0; kk < 2; ++kk) {
            bf16x8 a[2], b[4];
            int chunk = kk * 4 + lg;
            #pragma unroll
            for (int m = 0; m < 2; ++m) {
                int row = wy * 32 + m * 16 + lr;
                a[m] = *(bf16x8*)&Aw[row * 64 + ((chunk ^ (row & 7)) * 8)];
            }
            #pragma unroll
            for (int n = 0; n < 4; ++n) {
                int row = wx * 64 + n * 16 + lr;
                b[n] = *(bf16x8*)&Bh[row * 64 + ((chunk ^ (row & 7)) * 8)];
            }
            #pragma unroll
            for (int m = 0; m < 2; ++m)
                #pragma unroll
                for (int n = 0; n < 4; ++n)
                    acc[m][n] = __builtin_amdgcn_mfma_f32_16x16x32_bf16(a[m], b[n], acc[m][n], 0, 0, 0);
        }
    }
    #pragma unroll
    for (int m = 0; m < 2; ++m)
        #pragma unroll
        for (int n = 0; n < 4; ++n)
            #pragma unroll
            for (int r = 0; r < 4; ++r) {
                int gj = j0 + wy * 32 + m * 16 + lg * 4 + r;
                int gf = wx * 64 + n * 16 + lr;
                part[((size_t)p * NN + gj) * FF + gf] = (_Float16)acc[m][n][r];
            }
}

// out[j][f] = b[f] + dj*(dj*h[j][f] + sum_p part[p][j][f]), dj = rsqrt(deg+degc+1)
__global__ __launch_bounds__(256) void k_reduce(const _Float16* __restrict__ part,
                                                const float* __restrict__ h,
                                                const float* __restrict__ deg,
                                                const float* __restrict__ degc,
                                                const float* __restrict__ bvec,
                                                float* __restrict__ out) {
    int idx4 = blockIdx.x * 256 + threadIdx.x;   // 65536 groups of 4 f-elems
    int j = idx4 >> 5;
    int f4 = (idx4 & 31) * 4;
    size_t offh = (size_t)j * FF + f4;           // element offset
    const f16x4* p4 = (const f16x4*)part;
    float4 s = {0.f, 0.f, 0.f, 0.f};
    #pragma unroll
    for (int p = 0; p < NPART; ++p) {
        f16x4 v = p4[((size_t)p * NN * FF + offh) >> 2];
        s.x += (float)v[0]; s.y += (float)v[1];
        s.z += (float)v[2]; s.w += (float)v[3];
    }
    float dj = rsqrtf(deg[j] + degc[j] + 1.0f);
    float4 hv = *(const float4*)&h[offh];
    float4 bv = *(const float4*)&bvec[f4];
    float4 o;
    o.x = bv.x + dj * (dj * hv.x + s.x);
    o.y = bv.y + dj * (dj * hv.y + s.y);
    o.z = bv.z + dj * (dj * hv.z + s.z);
    o.w = bv.w + dj * (dj * hv.w + s.w);
    *(float4*)&out[offh] = o;
}

extern "C" void kernel_launch(void* const* d_in, const int* in_sizes, int n_in,
                              void* d_out, int out_size, void* d_ws, size_t ws_size,
                              hipStream_t stream) {
    const float* x = (const float*)d_in[0];   // [1,2048,128]
    const float* W = (const float*)d_in[1];   // [128,128]
    const float* b = (const float*)d_in[2];   // [128]
    float* out = (float*)d_out;

    if (ws_size < WS_NEEDED) return;  // insufficient scratch: fail visibly

    char* ws = (char*)d_ws;
    float*          deg   = (float*)(ws + OFF_DEG);
    float*          degc  = (float*)(ws + OFF_DEGC);
    uint32*         scal  = (uint32*)(ws + OFF_SCAL);
    uint32*         hist1 = (uint32*)(ws + OFF_HIST1);
    uint32*         hist2 = (uint32*)(ws + OFF_HIST2);
    float*          csumG = (float*)(ws + OFF_CSUM);
    float*          candV = (float*)(ws + OFF_CANDV);
    uint32*         candF = (uint32*)(ws + OFF_CANDF);
    float*          c2V   = (float*)(ws + OFF_C2V);
    uint32*         c2F   = (uint32*)(ws + OFF_C2F);
    unsigned short* xhi   = (unsigned short*)(ws + OFF_XHI);
    unsigned short* xlo   = (unsigned short*)(ws + OFF_XLO);
    float*          h     = (float*)(ws + OFF_H);
    float*          S     = (float*)(ws + OFF_S);
    _Float16*       part  = (_Float16*)(ws + OFF_PART);

    k_prep<<<128, 256, 0, stream>>>(x, xhi, xlo, (float4*)ws);
    k_main<<<384, 256, 0, stream>>>(x, W, xhi, xlo, S, hist1, h);
    k_h2c<<<512, 256, 0, stream>>>((const float4*)S, hist1, hist2, candV, candF, csumG, scal);
    k_filt<<<64, 256, 0, stream>>>(hist2, candV, candF, c2V, c2F, scal);
    k_degpick<<<64, 256, 0, stream>>>(csumG, candV, candF, c2V, c2F, scal, deg, degc);
    k_agg<<<dim3(32, NPART), 256, 0, stream>>>(S, h, deg, degc, scal, part);
    k_reduce<<<256, 256, 0, stream>>>(part, h, deg, degc, b, out);
}

// Round 18
// 89.522 us; speedup vs baseline: 1.1937x; 1.0008x over previous
//
#include <hip/hip_runtime.h>

typedef unsigned int uint32;
typedef __attribute__((ext_vector_type(8))) _Float16 f16x8;
typedef __attribute__((ext_vector_type(4))) _Float16 f16x4;
typedef __attribute__((ext_vector_type(8))) short bf16x8;
typedef __attribute__((ext_vector_type(4))) float f32x4;

#define NN 2048
#define FF 128
#define KEEPK 1258291u      // int(0.3 * 2048 * 2048)
#define NB 2048             // histogram bins per level
#define NCOPY1 4            // hist1 shards (256 sim writer blocks -> 64/shard)
#define CSHARDS 4           // colsum shards
#define LO1 (-4.0f)
#define BINW1 0.0625f       // 2^-4, exact
#define INV1 16.0f
#define INV2 32768.0f       // 2048 / BINW1 = 2^15, exact
#define CAND_CAP 131072u    // B1-bin population ~37k expected; 3.6x margin
#define LBUF 2048u          // per-block LDS candidate staging (k_h2c)
#define C2_CAP 4096u        // B2-filtered candidate capacity
#define NPART 16            // i-chunks for atomic-free aggregation (2 blocks/CU)
#define LO_SCALE 2048.0f    // 2^11: keep fp16 lo-part in normal range
#define LO_UNSCALE 4.8828125e-4f  // 2^-11

// workspace layout (bytes)  [ws_size = 256 MiB]
#define OFF_DEG    (0u)                 // float[2048]
#define OFF_DEGC   (8u*1024u)           // float[2048]
#define OFF_SCAL   (16u*1024u)          // uint[64]: 0=B1 1=K2 2=B2 3=need 5=c1 6=tau 7=cutoff 8=c2
#define OFF_HIST1  (17u*1024u)          // uint[4][2048] = 32K
#define OFF_HIST2  (49u*1024u)          // uint[2048] = 8K (unsharded)
#define OFF_CSUM   (57u*1024u)          // float[4][2048] = 32K
#define ZERO_BYTES (89u*1024u)          // region zeroed by k_prep
#define ZERO_F4    (5696u)              // ZERO_BYTES / 16
#define OFF_CANDV  (89u*1024u)          // float[131072] = 512K
#define OFF_CANDF  (601u*1024u)         // uint[131072]  = 512K
#define OFF_C2V    (1113u*1024u)        // float[4096] = 16K
#define OFF_C2F    (1129u*1024u)        // uint[4096]  = 16K
#define OFF_XHI    (1145u*1024u)        // fp16 hi(x) = 512K
#define OFF_XLO    (1657u*1024u)        // fp16 lo(x)*2048 = 512K
#define OFF_H      (2169u*1024u)        // float h = 1 MB
#define OFF_S      (3193u*1024u)        // float[2048*2048] = 16 MB
#define OFF_PART   (OFF_S + (uint32)NN*NN*4u)   // fp16[NPART][2048][128] = 8 MB
#define WS_NEEDED  ((size_t)OFF_PART + (size_t)NPART*NN*FF*2u)

__device__ __forceinline__ int bin_of(float v, float lo, float inv) {
    int b = (int)floorf((v - lo) * inv);
    return b < 0 ? 0 : (b > NB - 1 ? NB - 1 : b);
}

__device__ __forceinline__ unsigned short f2bf(float f) {   // round-to-nearest-even
    uint32 u = __float_as_uint(f);
    u += 0x7fffu + ((u >> 16) & 1u);
    return (unsigned short)(u >> 16);
}

__device__ __forceinline__ void split16(float v, unsigned short& hi, unsigned short& lo) {
    union { _Float16 f; unsigned short u; } a, b;
    a.f = (_Float16)v;
    float back = (float)a.f;
    b.f = (_Float16)((v - back) * LO_SCALE);
    hi = a.u; lo = b.u;
}

__device__ __forceinline__ uint4 pack8(const unsigned short* w) {  // 8 u16 -> uint4
    uint4 p;
    p.x = (uint32)w[0] | ((uint32)w[1] << 16);
    p.y = (uint32)w[2] | ((uint32)w[3] << 16);
    p.z = (uint32)w[4] | ((uint32)w[5] << 16);
    p.w = (uint32)w[6] | ((uint32)w[7] << 16);
    return p;
}

// one-shot split of x into fp16 hi/lo + fused zeroing of the accumulator region
__global__ __launch_bounds__(256) void k_prep(const float* __restrict__ x,
                                              unsigned short* __restrict__ xhi,
                                              unsigned short* __restrict__ xlo,
                                              float4* __restrict__ zbase) {
    int id = blockIdx.x * 256 + threadIdx.x;   // 32768 threads x 8 elems
    if ((uint32)id < ZERO_F4) zbase[id] = (float4){0.f, 0.f, 0.f, 0.f};
    float4 a0 = *(const float4*)&x[(size_t)id * 8];
    float4 a1 = *(const float4*)&x[(size_t)id * 8 + 4];
    unsigned short h8[8], l8[8];
    #pragma unroll
    for (int e = 0; e < 4; ++e) {
        split16((&a0.x)[e], h8[e], l8[e]);
        split16((&a1.x)[e], h8[4 + e], l8[4 + e]);
    }
    *(uint4*)&xhi[(size_t)id * 8] = pack8(h8);
    *(uint4*)&xlo[(size_t)id * 8] = pack8(l8);
}

// blocks [0,256): 128x128 tile of S = X*X^T - I (split-fp16 MFMA, fp32-accurate)
// + sharded hist1 (2 LDS copies). 4 waves (2x2), each 64x64 (4x4 16x16 frags).
// blocks [256,384): h = X*W (fp32, 16 rows per block).
__global__ __launch_bounds__(256) void k_main(const float* __restrict__ x,
                                              const float* __restrict__ W,
                                              const unsigned short* __restrict__ xhi,
                                              const unsigned short* __restrict__ xlo,
                                              float* __restrict__ S,
                                              uint32* __restrict__ hist1,
                                              float* __restrict__ h) {
    __shared__ unsigned short Ahi[128 * 128];  // 32 KB each
    __shared__ unsigned short Alo[128 * 128];
    __shared__ unsigned short Bhi[128 * 128];
    __shared__ unsigned short Blo[128 * 128];
    __shared__ uint32 hs[2][NB];               // 16 KB (2 copies)
    int bid = blockIdx.x;
    int t = threadIdx.x;

    if (bid >= 256) {   // ---- h = X*W path ----
        int r0 = (bid - 256) * 16;
        int row = t >> 4, fg = t & 15;
        float acc[8];
        #pragma unroll
        for (int e = 0; e < 8; ++e) acc[e] = 0.f;
        for (int k = 0; k < FF; ++k) {
            float xr = x[(size_t)(r0 + row) * FF + k];
            float4 w0 = *(const float4*)&W[k * FF + fg * 8];
            float4 w1 = *(const float4*)&W[k * FF + fg * 8 + 4];
            acc[0] += xr * w0.x; acc[1] += xr * w0.y;
            acc[2] += xr * w0.z; acc[3] += xr * w0.w;
            acc[4] += xr * w1.x; acc[5] += xr * w1.y;
            acc[6] += xr * w1.z; acc[7] += xr * w1.w;
        }
        float4 o0 = {acc[0], acc[1], acc[2], acc[3]};
        float4 o1 = {acc[4], acc[5], acc[6], acc[7]};
        *(float4*)&h[(size_t)(r0 + row) * FF + fg * 8] = o0;
        *(float4*)&h[(size_t)(r0 + row) * FF + fg * 8 + 4] = o1;
        return;
    }

    // ---- sim path: 128x128 tile ----
    for (int i = t; i < NB; i += 256) { hs[0][i] = 0; hs[1][i] = 0; }
    int i0 = (bid >> 4) * 128, j0 = (bid & 15) * 128;
    #pragma unroll
    for (int u = 0; u < 8; ++u) {
        int id = u * 256 + t;           // 2048 chunks per array (128 rows x 16)
        int r = id >> 4, c = id & 15;
        int sl = (c ^ (r & 7)) * 8;     // swizzled elem offset
        *(uint4*)&Ahi[r * 128 + sl] = *(const uint4*)&xhi[(size_t)(i0 + r) * FF + c * 8];
        *(uint4*)&Alo[r * 128 + sl] = *(const uint4*)&xlo[(size_t)(i0 + r) * FF + c * 8];
        *(uint4*)&Bhi[r * 128 + sl] = *(const uint4*)&xhi[(size_t)(j0 + r) * FF + c * 8];
        *(uint4*)&Blo[r * 128 + sl] = *(const uint4*)&xlo[(size_t)(j0 + r) * FF + c * 8];
    }
    __syncthreads();

    int wid = t >> 6, l = t & 63;
    int wy = wid >> 1, wx = wid & 1;
    int lr = l & 15, lg = l >> 4;
    f32x4 acc1[4][4], acc2[4][4];
    #pragma unroll
    for (int m = 0; m < 4; ++m)
        #pragma unroll
        for (int n = 0; n < 4; ++n) {
            acc1[m][n] = (f32x4){0.f, 0.f, 0.f, 0.f};
            acc2[m][n] = (f32x4){0.f, 0.f, 0.f, 0.f};
        }

    #pragma unroll
    for (int kk = 0; kk < 4; ++kk) {
        f16x8 ah[4], al[4], bh[4], bl[4];
        int chunk = kk * 4 + lg;
        #pragma unroll
        for (int m = 0; m < 4; ++m) {
            int row = wy * 64 + m * 16 + lr;
            int off = row * 128 + ((chunk ^ (row & 7)) * 8);
            ah[m] = *(f16x8*)&Ahi[off];
            al[m] = *(f16x8*)&Alo[off];
        }
        #pragma unroll
        for (int n = 0; n < 4; ++n) {
            int row = wx * 64 + n * 16 + lr;
            int off = row * 128 + ((chunk ^ (row & 7)) * 8);
            bh[n] = *(f16x8*)&Bhi[off];
            bl[n] = *(f16x8*)&Blo[off];
        }
        #pragma unroll
        for (int m = 0; m < 4; ++m)
            #pragma unroll
            for (int n = 0; n < 4; ++n) {
                acc1[m][n] = __builtin_amdgcn_mfma_f32_16x16x32_f16(ah[m], bh[n], acc1[m][n], 0, 0, 0);
                acc2[m][n] = __builtin_amdgcn_mfma_f32_16x16x32_f16(ah[m], bl[n], acc2[m][n], 0, 0, 0);
                acc2[m][n] = __builtin_amdgcn_mfma_f32_16x16x32_f16(al[m], bh[n], acc2[m][n], 0, 0, 0);
            }
    }

    // C-write (col=lane&15, row=(lane>>4)*4+reg) + fused hist (copy by t&1)
    uint32* hrow = hs[t & 1];
    #pragma unroll
    for (int m = 0; m < 4; ++m) {
        #pragma unroll
        for (int n = 0; n < 4; ++n) {
            #pragma unroll
            for (int r = 0; r < 4; ++r) {
                int gi = i0 + wy * 64 + m * 16 + lg * 4 + r;
                int gj = j0 + wx * 64 + n * 16 + lr;
                float v = acc1[m][n][r] + acc2[m][n][r] * LO_UNSCALE;
                if (gi == gj) v -= 1.0f;          // subtract eye
                S[(size_t)gi * NN + gj] = v;
                atomicAdd(&hrow[bin_of(v, LO1, INV1)], 1u);
            }
        }
    }
    __syncthreads();
    uint32* hcopy = &hist1[(uint32)(bid & (NCOPY1 - 1)) * NB];
    for (int i = t; i < NB; i += 256) {
        uint32 v = hs[0][i] + hs[1][i];
        if (v) atomicAdd(&hcopy[i], v);
    }
}

// fused scan1 + level-2 histogram + candidate gather + colsum-above-B1.
__global__ __launch_bounds__(256) void k_h2c(const float4* __restrict__ S4,
                                             const uint32* __restrict__ hist1,
                                             uint32* __restrict__ hist2,
                                             float* __restrict__ candV,
                                             uint32* __restrict__ candF,
                                             float* __restrict__ csumG,
                                             uint32* __restrict__ scal) {
    __shared__ uint32 hs[NB];        // 8 KB: first merged hist1, then level-2 hist
    __shared__ uint32 csum[256];     // 1 KB
    __shared__ float  cs2[4][256];   // 4 KB  per-rowgroup column sums
    __shared__ float  bvv[LBUF];     // 8 KB
    __shared__ uint32 bff[LBUF];     // 8 KB
    __shared__ uint32 bcnt, gbase, sB1;
    int t = threadIdx.x;
    int cw = blockIdx.x & 7;         // column window: 256 cols
    int rg = blockIdx.x >> 3;        // row group: 32 rows (64 groups)

    // ---- phase 0: merge hist1 shards, scan for B1/K2 (redundant per block) ----
    {
        uint32 s8[8];
        #pragma unroll
        for (int u = 0; u < 8; ++u) s8[u] = 0;
        #pragma unroll
        for (int cp = 0; cp < NCOPY1; ++cp) {
            const uint4* hp = (const uint4*)&hist1[cp * NB + t * 8];
            uint4 a = hp[0], b = hp[1];
            s8[0] += a.x; s8[1] += a.y; s8[2] += a.z; s8[3] += a.w;
            s8[4] += b.x; s8[5] += b.y; s8[6] += b.z; s8[7] += b.w;
        }
        uint32 tot = 0;
        #pragma unroll
        for (int u = 0; u < 8; ++u) { hs[t * 8 + u] = s8[u]; tot += s8[u]; }
        csum[t] = tot;
    }
    if (t == 0) bcnt = 0;
    __syncthreads();
    if (t == 0) {
        uint32 K = KEEPK, cum = 0;
        int cb = 255;
        for (; cb > 0; --cb) {
            if (cum + csum[cb] >= K) break;
            cum += csum[cb];
        }
        int b;
        for (b = cb * 8 + 7; b > cb * 8; --b) {
            if (cum + hs[b] >= K) break;
            cum += hs[b];
        }
        sB1 = (uint32)b;
        scal[0] = (uint32)b;      // B1 (same value from every block)
        scal[1] = K - cum;        // K2 (same value from every block)
    }
    __syncthreads();
    int B1 = (int)sB1;
    // re-zero hs for the level-2 histogram
    for (int i = t; i < NB; i += 256) hs[i] = 0;
    __syncthreads();

    float lo2 = LO1 + (float)B1 * BINW1;
    int rown = t >> 6;               // 0..3
    int c64 = t & 63;                // float4-group within window
    int colbase = cw * 256 + c64 * 4;
    float creg[4] = {0.f, 0.f, 0.f, 0.f};
    #pragma unroll
    for (int it = 0; it < 8; ++it) {
        int row = rg * 32 + it * 4 + rown;
        float4 v = S4[(size_t)row * (NN / 4) + cw * 64 + c64];
        #pragma unroll
        for (int e = 0; e < 4; ++e) {
            float xv = (&v.x)[e];
            int b1 = bin_of(xv, LO1, INV1);
            if (b1 > B1) {
                creg[e] += xv;
            } else if (b1 == B1) {
                atomicAdd(&hs[bin_of(xv, lo2, INV2)], 1u);
                uint32 p = atomicAdd(&bcnt, 1u);
                uint32 flat = (uint32)row * (uint32)NN + (uint32)(colbase + e);
                if (p < LBUF) { bvv[p] = xv; bff[p] = flat; }
                else {  // overflow safety (statistically unreachable)
                    uint32 g = atomicAdd(&scal[5], 1u);
                    if (g < CAND_CAP) { candV[g] = xv; candF[g] = flat; }
                }
            }
        }
    }
    #pragma unroll
    for (int e = 0; e < 4; ++e) cs2[rown][c64 * 4 + e] = creg[e];
    __syncthreads();
    {   // thread t owns window-column t; 4 shards
        float s = cs2[0][t] + cs2[1][t] + cs2[2][t] + cs2[3][t];
        uint32 shard = (uint32)(blockIdx.x & (CSHARDS - 1));
        if (s != 0.f) atomicAdd(&csumG[shard * NN + cw * 256 + t], s);
    }
    uint32 n = bcnt > LBUF ? LBUF : bcnt;
    if (t == 0) gbase = atomicAdd(&scal[5], n);
    __syncthreads();
    uint32 gb = gbase;
    for (uint32 i = t; i < n; i += 256u) {
        uint32 g = gb + i;
        if (g < CAND_CAP) { candV[g] = bvv[i]; candF[g] = bff[i]; }
    }
    for (int i = t; i < NB; i += 256) {
        uint32 v = hs[i];
        if (v) atomicAdd(&hist2[i], v);
    }
}

// fused scan2+filter: each block redundantly scans hist2 (8 KB, L2) -> B2/need,
// then filters B1-candidates to bin B2 (LDS-staged, one global atomic per block).
__global__ __launch_bounds__(256) void k_filt(const uint32* __restrict__ hist2,
                                              const float* __restrict__ candV,
                                              const uint32* __restrict__ candF,
                                              float* __restrict__ c2V,
                                              uint32* __restrict__ c2F,
                                              uint32* __restrict__ scal) {
    __shared__ uint32 sh[NB];        // 8 KB
    __shared__ uint32 csum[256];
    __shared__ float  fv[1024];
    __shared__ uint32 ff[1024];
    __shared__ uint32 fcnt, fbase, sB2;
    int t = threadIdx.x;
    if (t == 0) fcnt = 0;
    // inline level-2 scan (same in every block; deterministic)
    uint32 tot = 0;
    #pragma unroll
    for (int u = 0; u < 8; ++u) {
        uint32 s = hist2[t * 8 + u];
        sh[t * 8 + u] = s; tot += s;
    }
    csum[t] = tot;
    __syncthreads();
    if (t == 0) {
        uint32 K = scal[1], cum = 0;
        int cb = 255;
        for (; cb > 0; --cb) {
            if (cum + csum[cb] >= K) break;
            cum += csum[cb];
        }
        int b;
        for (b = cb * 8 + 7; b > cb * 8; --b) {
            if (cum + sh[b] >= K) break;
            cum += sh[b];
        }
        sB2 = (uint32)b;
        if (blockIdx.x == 0) {
            scal[2] = (uint32)b;     // B2 (for reference)
            scal[3] = K - cum;       // need within B2 (k_degpick reads this)
        }
    }
    __syncthreads();
    uint32 cnt = scal[5];
    if (cnt > CAND_CAP) cnt = CAND_CAP;
    int B1 = (int)scal[0], B2 = (int)sB2;
    float lo2 = LO1 + (float)B1 * BINW1;
    for (uint32 i = blockIdx.x * 256u + t; i < cnt; i += gridDim.x * 256u) {
        float v = candV[i];
        if (bin_of(v, lo2, INV2) == B2) {
            uint32 p = atomicAdd(&fcnt, 1u);
            if (p < 1024u) { fv[p] = v; ff[p] = candF[i]; }
            else {  // overflow safety
                uint32 g = atomicAdd(&scal[8], 1u);
                if (g < C2_CAP) { c2V[g] = v; c2F[g] = candF[i]; }
            }
        }
    }
    __syncthreads();
    uint32 n = fcnt > 1024u ? 1024u : fcnt;
    if (t == 0) fbase = atomicAdd(&scal[8], n);
    __syncthreads();
    uint32 fb = fbase;
    for (uint32 i = t; i < n; i += 256u) {
        uint32 g = fb + i;
        if (g < C2_CAP) { c2V[g] = fv[i]; c2F[g] = ff[i]; }
    }
}

// fused pick + degsum: every block redundantly computes exact tau/cutoff from
// the tiny B2-filtered list (deterministic), block 0 persists to scal; then
// deg[j] = merged colsum shards, degc[j] += selected B1-bin candidates.
__global__ __launch_bounds__(256) void k_degpick(const float* __restrict__ csumG,
                                                 const float* __restrict__ candV,
                                                 const uint32* __restrict__ candF,
                                                 const float* __restrict__ c2V,
                                                 const uint32* __restrict__ c2F,
                                                 uint32* __restrict__ scal,
                                                 float* __restrict__ deg,
                                                 float* __restrict__ degc) {
    __shared__ float  sv[C2_CAP];
    __shared__ uint32 sf[C2_CAP];
    __shared__ float  s_tau;
    __shared__ uint32 s_cut;
    int t = threadIdx.x;
    int tid = blockIdx.x * 256 + t;   // 64 blocks x 256 = 16384
    uint32 c2 = scal[8];
    if (c2 > C2_CAP) c2 = C2_CAP;
    for (uint32 i = t; i < c2; i += 256u) { sv[i] = c2V[i]; sf[i] = c2F[i]; }
    // deg merge (independent of tau)
    if (tid < NN) {
        float s = 0.f;
        #pragma unroll
        for (int cp = 0; cp < CSHARDS; ++cp) s += csumG[cp * NN + tid];
        deg[tid] = s;
    }
    __syncthreads();
    if (t == 0) {
        uint32 need = scal[3];
        if (need > c2) need = c2;
        if (c2 == 0) {
            s_tau = 3.0e38f; s_cut = 0u;
        } else {
            if (need == 0) need = 1;
            for (uint32 s = 0; s < need; ++s) {
                uint32 best = s;
                for (uint32 q = s + 1; q < c2; ++q) {
                    if (sv[q] > sv[best] || (sv[q] == sv[best] && sf[q] < sf[best])) best = q;
                }
                float tv = sv[s]; sv[s] = sv[best]; sv[best] = tv;
                uint32 tf = sf[s]; sf[s] = sf[best]; sf[best] = tf;
            }
            s_tau = sv[need - 1];
            s_cut = sf[need - 1];
        }
        if (blockIdx.x == 0) {
            scal[6] = __float_as_uint(s_tau);   // tau (for k_agg)
            scal[7] = s_cut;                    // cutoff
        }
    }
    __syncthreads();
    float tau = s_tau;
    uint32 cutoff = s_cut;
    uint32 cnt = scal[5];
    if (cnt > CAND_CAP) cnt = CAND_CAP;
    for (uint32 i = (uint32)tid; i < cnt; i += 16384u) {
        float v = candV[i];
        uint32 flat = candF[i];
        if (v > tau || (v == tau && flat <= cutoff))
            atomicAdd(&degc[flat & (NN - 1)], v);
    }
}

// part[p][j][f] = sum_{i in chunk p} sel(i,j)*S[i][j]*dinv[i]*h[i][f] via bf16 MFMA.
// NPART=16 -> 512 blocks -> 2 blocks/CU (staging of one overlaps MFMA of other).
__global__ __launch_bounds__(256) void k_agg(const float* __restrict__ S,
                                             const float* __restrict__ h,
                                             const float* __restrict__ deg,
                                             const float* __restrict__ degc,
                                             const uint32* __restrict__ scal,
                                             _Float16* __restrict__ part) {
    __shared__ unsigned short Aw[64 * 64];    // 8 KB, [j][i] swizzled
    __shared__ unsigned short Bh[128 * 64];   // 16 KB, [f][i] swizzled
    int t = threadIdx.x;
    int j0 = blockIdx.x * 64;
    int p = blockIdx.y;
    int ibase = p * (NN / NPART);   // 128 rows per part
    float tau = __uint_as_float(scal[6]);
    uint32 cutoff = scal[7];
    int wid = t >> 6, l = t & 63;
    int wy = wid >> 1, wx = wid & 1;
    int lr = l & 15, lg = l >> 4;

    f32x4 acc[2][4];
    #pragma unroll
    for (int m = 0; m < 2; ++m)
        #pragma unroll
        for (int n = 0; n < 4; ++n) acc[m][n] = (f32x4){0.f, 0.f, 0.f, 0.f};

    #pragma unroll
    for (int cc = 0; cc < (NN / NPART) / 64; ++cc) {   // 2 iterations
        int ib = ibase + cc * 64;
        __syncthreads();
        // stage A: masked S row-reads -> bf16
        #pragma unroll
        for (int u = 0; u < 2; ++u) {
            int id = u * 256 + t;
            int r = id >> 3, c = id & 7;
            int gj = j0 + r;
            unsigned short w8[8];
            #pragma unroll
            for (int q = 0; q < 2; ++q) {
                float4 v = *(const float4*)&S[(size_t)gj * NN + ib + c * 8 + q * 4];
                #pragma unroll
                for (int e = 0; e < 4; ++e) {
                    int gi = ib + c * 8 + q * 4 + e;
                    float vv = (&v.x)[e];
                    uint32 flat = (uint32)gi * (uint32)NN + (uint32)gj;
                    bool sel = (vv > tau) || (vv == tau && flat <= cutoff);
                    w8[q * 4 + e] = f2bf(sel ? vv : 0.f);
                }
            }
            *(uint4*)&Aw[r * 64 + ((c ^ (r & 7)) * 8)] = pack8(w8);
        }
        // stage B: transpose dinv-scaled h -> [f][i] bf16, swizzled
        {
            int i = t & 63, fh = (t >> 6) * 32;
            int gi = ib + i;
            float di = rsqrtf(deg[gi] + degc[gi] + 1.0f);
            #pragma unroll
            for (int q = 0; q < 8; ++q) {
                int f = fh + q * 4;
                float4 hv = *(const float4*)&h[(size_t)gi * FF + f];
                #pragma unroll
                for (int e = 0; e < 4; ++e) {
                    int fr = f + e;
                    Bh[fr * 64 + (((i >> 3) ^ (fr & 7)) * 8 + (i & 7))] =
                        f2bf((&hv.x)[e] * di);
                }
            }
        }
        __syncthreads();
        #pragma unroll
        for (int kk = 0; kk < 2; ++kk) {
            bf16x8 a[2], b[4];
            int chunk = kk * 4 + lg;
            #pragma unroll
            for (int m = 0; m < 2; ++m) {
                int row = wy * 32 + m * 16 + lr;
                a[m] = *(bf16x8*)&Aw[row * 64 + ((chunk ^ (row & 7)) * 8)];
            }
            #pragma unroll
            for (int n = 0; n < 4; ++n) {
                int row = wx * 64 + n * 16 + lr;
                b[n] = *(bf16x8*)&Bh[row * 64 + ((chunk ^ (row & 7)) * 8)];
            }
            #pragma unroll
            for (int m = 0; m < 2; ++m)
                #pragma unroll
                for (int n = 0; n < 4; ++n)
                    acc[m][n] = __builtin_amdgcn_mfma_f32_16x16x32_bf16(a[m], b[n], acc[m][n], 0, 0, 0);
        }
    }
    #pragma unroll
    for (int m = 0; m < 2; ++m)
        #pragma unroll
        for (int n = 0; n < 4; ++n)
            #pragma unroll
            for (int r = 0; r < 4; ++r) {
                int gj = j0 + wy * 32 + m * 16 + lg * 4 + r;
                int gf = wx * 64 + n * 16 + lr;
                part[((size_t)p * NN + gj) * FF + gf] = (_Float16)acc[m][n][r];
            }
}

// out[j][f] = b[f] + dj*(dj*h[j][f] + sum_p part[p][j][f]), dj = rsqrt(deg+degc+1)
__global__ __launch_bounds__(256) void k_reduce(const _Float16* __restrict__ part,
                                                const float* __restrict__ h,
                                                const float* __restrict__ deg,
                                                const float* __restrict__ degc,
                                                const float* __restrict__ bvec,
                                                float* __restrict__ out) {
    int idx4 = blockIdx.x * 256 + threadIdx.x;   // 65536 groups of 4 f-elems
    int j = idx4 >> 5;
    int f4 = (idx4 & 31) * 4;
    size_t offh = (size_t)j * FF + f4;           // element offset
    const f16x4* p4 = (const f16x4*)part;
    float4 s = {0.f, 0.f, 0.f, 0.f};
    #pragma unroll
    for (int p = 0; p < NPART; ++p) {
        f16x4 v = p4[((size_t)p * NN * FF + offh) >> 2];
        s.x += (float)v[0]; s.y += (float)v[1];
        s.z += (float)v[2]; s.w += (float)v[3];
    }
    float dj = rsqrtf(deg[j] + degc[j] + 1.0f);
    float4 hv = *(const float4*)&h[offh];
    float4 bv = *(const float4*)&bvec[f4];
    float4 o;
    o.x = bv.x + dj * (dj * hv.x + s.x);
    o.y = bv.y + dj * (dj * hv.y + s.y);
    o.z = bv.z + dj * (dj * hv.z + s.z);
    o.w = bv.w + dj * (dj * hv.w + s.w);
    *(float4*)&out[offh] = o;
}

extern "C" void kernel_launch(void* const* d_in, const int* in_sizes, int n_in,
                              void* d_out, int out_size, void* d_ws, size_t ws_size,
                              hipStream_t stream) {
    const float* x = (const float*)d_in[0];   // [1,2048,128]
    const float* W = (const float*)d_in[1];   // [128,128]
    const float* b = (const float*)d_in[2];   // [128]
    float* out = (float*)d_out;

    if (ws_size < WS_NEEDED) return;  // insufficient scratch: fail visibly

    char* ws = (char*)d_ws;
    float*          deg   = (float*)(ws + OFF_DEG);
    float*          degc  = (float*)(ws + OFF_DEGC);
    uint32*         scal  = (uint32*)(ws + OFF_SCAL);
    uint32*         hist1 = (uint32*)(ws + OFF_HIST1);
    uint32*         hist2 = (uint32*)(ws + OFF_HIST2);
    float*          csumG = (float*)(ws + OFF_CSUM);
    float*          candV = (float*)(ws + OFF_CANDV);
    uint32*         candF = (uint32*)(ws + OFF_CANDF);
    float*          c2V   = (float*)(ws + OFF_C2V);
    uint32*         c2F   = (uint32*)(ws + OFF_C2F);
    unsigned short* xhi   = (unsigned short*)(ws + OFF_XHI);
    unsigned short* xlo   = (unsigned short*)(ws + OFF_XLO);
    float*          h     = (float*)(ws + OFF_H);
    float*          S     = (float*)(ws + OFF_S);
    _Float16*       part  = (_Float16*)(ws + OFF_PART);

    k_prep<<<128, 256, 0, stream>>>(x, xhi, xlo, (float4*)ws);
    k_main<<<384, 256, 0, stream>>>(x, W, xhi, xlo, S, hist1, h);
    k_h2c<<<512, 256, 0, stream>>>((const float4*)S, hist1, hist2, candV, candF, csumG, scal);
    k_filt<<<64, 256, 0, stream>>>(hist2, candV, candF, c2V, c2F, scal);
    k_degpick<<<64, 256, 0, stream>>>(csumG, candV, candF, c2V, c2F, scal, deg, degc);
    k_agg<<<dim3(32, NPART), 256, 0, stream>>>(S, h, deg, degc, scal, part);
    k_reduce<<<256, 256, 0, stream>>>(part, h, deg, degc, b, out);
}